// Round 7
// baseline (1266.541 us; speedup 1.0000x reference)
//
#include <hip/hip_runtime.h>
#include <hip/hip_bf16.h>
#include <stdint.h>

#define Bb 4
#define Ss 8192
#define Hh 2048
#define NHh 16
#define DHh 128
#define DFFf 8192
#define KS 1024
#define NTOK 4096

typedef unsigned short u16;
typedef __bf16 bf16x8 __attribute__((ext_vector_type(8)));
typedef float f32x4 __attribute__((ext_vector_type(4)));

union B8 { uint4 u; bf16x8 v; u16 s[8]; };

__device__ __forceinline__ float b2f(u16 x) { return __uint_as_float(((unsigned)x) << 16); }
__device__ __forceinline__ u16 f2b(float x) {
  __hip_bfloat16 h = __float2bfloat16(x);
  return *reinterpret_cast<u16*>(&h);
}

__device__ __forceinline__ void gll16(const void* g, void* l) {
  __builtin_amdgcn_global_load_lds((const __attribute__((address_space(1))) void*)g,
                                   (__attribute__((address_space(3))) void*)l, 16, 0, 0);
}

// swizzled 16B-unit index within a Rx32 bf16 region (row-pair XOR swizzle)
__device__ __forceinline__ int swz16(int r, int cg) {
  int u = ((r & 1) << 2) | cg;
  return ((r >> 1) << 3) | (u ^ ((r >> 1) & 7));
}

// ---------------- top-k index scan ----------------
__global__ void topk_prep(const void* maskp, const int* __restrict__ posids,
                          const float* __restrict__ scores,
                          int* __restrict__ idx, int* __restrict__ posg,
                          float* __restrict__ scalev) {
  int b = blockIdx.x;
  int tid = threadIdx.x, lane = tid & 63, wv = tid >> 6;
  __shared__ int wsum[4];
  __shared__ int base;
  __shared__ int mode;
  __shared__ int detCnt;
  if (tid == 0) { base = 0; detCnt = 0; }
  __syncthreads();
  {
    const unsigned char* mb = (const unsigned char*)maskp;
    int c = 0;
    for (int s = tid; s < 8192; s += 256) c += (mb[s] != 0);
    atomicAdd(&detCnt, c);
  }
  __syncthreads();
  if (tid == 0) mode = (detCnt == KS) ? 1 : 0;
  __syncthreads();
  const unsigned char* mb = (const unsigned char*)maskp;
  const int* mi = (const int*)maskp;
  for (int s0 = 0; s0 < Ss; s0 += 256) {
    int s = s0 + tid;
    int pred = mode ? (mb[(size_t)b * Ss + s] != 0) : (mi[(size_t)b * Ss + s] != 0);
    unsigned long long bal = __ballot(pred);
    int lp = __popcll(bal & ((1ull << lane) - 1ull));
    int wtot = __popcll(bal);
    if (lane == 0) wsum[wv] = wtot;
    __syncthreads();
    int woff = 0;
    for (int w = 0; w < wv; ++w) woff += wsum[w];
    int tot = wsum[0] + wsum[1] + wsum[2] + wsum[3];
    int p = base + woff + lp;
    if (pred && p < KS) {
      idx[b * KS + p] = s;
      posg[b * KS + p] = posids[(size_t)b * Ss + s];
    }
    __syncthreads();
    if (tid == 0) base += tot;
    __syncthreads();
  }
  if (b == 0 && tid < Bb) scalev[tid] = 0.5f * 1.0f + (scores[tid] - 0.5f) * 1.0f;
}

// ---------------- weight transpose fp32 -> bf16 ----------------
__global__ void transpose_w(const float* __restrict__ in, u16* __restrict__ out, int R, int C) {
  __shared__ float tile[32][33];
  int tx = threadIdx.x, ty = threadIdx.y;
  int c0 = blockIdx.x * 32, r0 = blockIdx.y * 32;
  for (int j = ty; j < 32; j += 8) tile[j][tx] = in[(size_t)(r0 + j) * C + c0 + tx];
  __syncthreads();
  for (int j = ty; j < 32; j += 8) out[(size_t)(c0 + j) * R + r0 + tx] = f2b(tile[tx][j]);
}

// ---------------- RMSNorm ----------------
template <int GATHER>
__global__ __launch_bounds__(256) void rmsnorm_k(const float* __restrict__ src0,
                                                 const int* __restrict__ idx,
                                                 const float* __restrict__ w,
                                                 u16* __restrict__ out) {
  int t = blockIdx.x;
  const float* src;
  if (GATHER) { int b = t >> 10; src = src0 + ((size_t)b * Ss + idx[t]) * Hh; }
  else src = src0 + (size_t)t * Hh;
  int tid = threadIdx.x, lane = tid & 63, wv = tid >> 6;
  float4 x0 = *(const float4*)(src + tid * 8);
  float4 x1 = *(const float4*)(src + tid * 8 + 4);
  float ss = x0.x * x0.x + x0.y * x0.y + x0.z * x0.z + x0.w * x0.w +
             x1.x * x1.x + x1.y * x1.y + x1.z * x1.z + x1.w * x1.w;
  for (int o = 32; o; o >>= 1) ss += __shfl_down(ss, o);
  __shared__ float wred[4];
  if (lane == 0) wred[wv] = ss;
  __syncthreads();
  float tot = wred[0] + wred[1] + wred[2] + wred[3];
  float r = rsqrtf(tot * (1.0f / Hh) + 1e-5f);
  const float* wp = w + tid * 8;
  u16* op = out + (size_t)t * Hh + tid * 8;
  float xs[8] = {x0.x, x0.y, x0.z, x0.w, x1.x, x1.y, x1.z, x1.w};
#pragma unroll
  for (int j = 0; j < 8; ++j) op[j] = f2b(xs[j] * r * wp[j]);
}

// ---------------- 256x256 8-phase bf16 GEMM, pair-unrolled, const offsets ----------------
template <int EPI>
__global__ __launch_bounds__(512, 2) void gemm256(
    const u16* __restrict__ A, const u16* __restrict__ Bt,
    int N, int Kd, int lda, int gm, int gw,
    u16* __restrict__ Cb,
    const float* __restrict__ hid, const int* __restrict__ idx,
    const float* __restrict__ hs2, const float* __restrict__ scalev,
    float* __restrict__ Cf) {
  __shared__ u16 lds[65536];
  int bid = blockIdx.x;
  int xcd = bid & 7;
  int i2 = bid >> 3;
  int bm = i2 / gw;             // bn-fast within XCD strip
  int bn = xcd * gw + i2 % gw;
  int m0 = bm * 256, n0 = bn * 256;
  int tid = threadIdx.x, lane = tid & 63, wv = tid >> 6;
  int wm = wv >> 2, wn = wv & 3;
  int NT = Kd >> 6;

  int P16 = wv * 64 + lane;
  int blk = P16 >> 3, up = P16 & 7;
  int uu = up ^ (blk & 7);
  int r0 = blk * 2 + (uu >> 2), cg0 = uu & 3;
  const u16* srcA = A + (size_t)(m0 + r0) * lda + cg0 * 8;
  const u16* srcB = Bt + (size_t)(n0 + r0) * Kd + cg0 * 8;
  size_t rsA = (size_t)128 * lda, rsB = (size_t)128 * Kd;

  int offA = swz16(wm * 128 + (lane & 15), lane >> 4) * 8;
  int offB = 32768 + swz16(wn * 64 + (lane & 15), lane >> 4) * 8;
  u16* ldsw = &lds[wv * 512];

  f32x4 acc[8][4] = {};
  B8 aR[4], bR[4];

  // prologue: 7 halves (t0 full, t1 minus A.kk1)
  gll16(srcB,      ldsw + 32768); gll16(srcB + rsB,      ldsw + 36864);
  gll16(srcA,      ldsw +     0); gll16(srcA + rsA,      ldsw +  4096);
  gll16(srcB + 32, ldsw + 40960); gll16(srcB + 32 + rsB, ldsw + 45056);
  gll16(srcA + 32, ldsw +  8192); gll16(srcA + 32 + rsA, ldsw + 12288);
  gll16(srcB + 64, ldsw + 49152); gll16(srcB + 64 + rsB, ldsw + 53248);
  gll16(srcA + 64, ldsw + 16384); gll16(srcA + 64 + rsA, ldsw + 20480);
  gll16(srcB + 96, ldsw + 57344); gll16(srcB + 96 + rsB, ldsw + 61440);
  asm volatile("s_waitcnt vmcnt(6)" ::: "memory");
  asm volatile("s_barrier" ::: "memory");

  const u16* stA = srcA + 64;
  const u16* stB = srcB + 64;

  auto phase = [&](int abase, int bbase, int mh) {
    if (mh == 0) {
#pragma unroll
      for (int nf = 0; nf < 4; ++nf) bR[nf].u = *(const uint4*)&lds[offB + bbase + nf * 512];
    }
#pragma unroll
    for (int i3 = 0; i3 < 4; ++i3)
      aR[i3].u = *(const uint4*)&lds[offA + abase + (i3 + 4 * mh) * 512];
  };
  auto mfma16 = [&](int mh) {
    asm volatile("s_barrier" ::: "memory");
    asm volatile("s_waitcnt lgkmcnt(0)" ::: "memory");
    __builtin_amdgcn_s_setprio(1);
#pragma unroll
    for (int nf = 0; nf < 4; ++nf)
#pragma unroll
      for (int i3 = 0; i3 < 4; ++i3)
        acc[mh * 4 + i3][nf] =
            __builtin_amdgcn_mfma_f32_16x16x32_bf16(aR[i3].v, bR[nf].v, acc[mh * 4 + i3][nf], 0, 0, 0);
    __builtin_amdgcn_s_setprio(0);
  };

  for (int ktp = 0; ktp < NT; ktp += 2) {
    bool sAll = (ktp < NT - 2);
    // ===== even body (d=0) =====
    phase(0, 0, 0);
    { gll16(stA + 32, ldsw + 24576); gll16(stA + 32 + rsA, ldsw + 28672); }
    mfma16(0);
    asm volatile("s_barrier" ::: "memory");
    phase(0, 0, 1);
    if (sAll) { gll16(stB + 64, ldsw + 32768); gll16(stB + 64 + rsB, ldsw + 36864); }
    mfma16(1);
    asm volatile("s_barrier" ::: "memory");
    phase(8192, 8192, 0);
    if (sAll) { gll16(stA + 64, ldsw + 0); gll16(stA + 64 + rsA, ldsw + 4096); }
    mfma16(0);
    asm volatile("s_barrier" ::: "memory");
    phase(8192, 8192, 1);
    if (sAll) { gll16(stB + 96, ldsw + 40960); gll16(stB + 96 + rsB, ldsw + 45056); }
    mfma16(1);
    if (sAll) asm volatile("s_waitcnt vmcnt(6)" ::: "memory");
    else asm volatile("s_waitcnt vmcnt(0)" ::: "memory");
    asm volatile("s_barrier" ::: "memory");
    // ===== odd body (d=1) =====
    phase(16384, 16384, 0);
    if (sAll) { gll16(stA + 96, ldsw + 8192); gll16(stA + 96 + rsA, ldsw + 12288); }
    mfma16(0);
    asm volatile("s_barrier" ::: "memory");
    phase(16384, 16384, 1);
    if (sAll) { gll16(stB + 128, ldsw + 49152); gll16(stB + 128 + rsB, ldsw + 53248); }
    mfma16(1);
    asm volatile("s_barrier" ::: "memory");
    phase(24576, 24576, 0);
    if (sAll) { gll16(stA + 128, ldsw + 16384); gll16(stA + 128 + rsA, ldsw + 20480); }
    mfma16(0);
    asm volatile("s_barrier" ::: "memory");
    phase(24576, 24576, 1);
    if (sAll) { gll16(stB + 160, ldsw + 57344); gll16(stB + 160 + rsB, ldsw + 61440); }
    mfma16(1);
    if (sAll) asm volatile("s_waitcnt vmcnt(6)" ::: "memory");
    asm volatile("s_barrier" ::: "memory");
    stA += 128; stB += 128;
  }

#pragma unroll
  for (int mf = 0; mf < 8; ++mf) {
#pragma unroll
    for (int rr = 0; rr < 4; ++rr) {
      int row = m0 + wm * 128 + mf * 16 + (lane >> 4) * 4 + rr;
#pragma unroll
      for (int nf = 0; nf < 4; ++nf) {
        int col = n0 + wn * 64 + nf * 16 + (lane & 15);
        float v = acc[mf][nf][rr];
        if (EPI == 0) {
          Cb[(size_t)row * N + col] = f2b(v);
        } else if (EPI == 1) {
          int b = row >> 10;
          Cf[(size_t)row * Hh + col] = hid[((size_t)b * Ss + idx[row]) * Hh + col] + v;
        } else {
          int b = row >> 10;
          Cf[((size_t)b * Ss + idx[row]) * Hh + col] = hs2[(size_t)row * Hh + col] + v * scalev[b];
        }
      }
    }
  }
}

// ---------------- 128x256 bf16 GEMM, 4-slot pipeline, pair-unrolled ----------------
template <int EPI>
__global__ __launch_bounds__(512, 2) void gemm128(
    const u16* __restrict__ A, const u16* __restrict__ Bt,
    int N, int Kd, int lda, int gm, int gw,
    u16* __restrict__ Cb,
    const float* __restrict__ hid, const int* __restrict__ idx,
    const float* __restrict__ hs2, const float* __restrict__ scalev,
    float* __restrict__ Cf) {
  __shared__ u16 lds[49152];
  int bid = blockIdx.x;
  int xcd = bid & 7;
  int i2 = bid >> 3;
  int bm = i2 / gw;
  int bn = xcd * gw + i2 % gw;
  int m0 = bm * 128, n0 = bn * 256;
  int tid = threadIdx.x, lane = tid & 63, wv = tid >> 6;
  int wm = wv >> 2, wn = wv & 3;
  int NT = Kd >> 6;

  int P16 = wv * 64 + lane;
  int blk = P16 >> 3, up = P16 & 7;
  int uu = up ^ (blk & 7);
  int r0 = blk * 2 + (uu >> 2), cg0 = uu & 3;
  const u16* srcA = A + (size_t)(m0 + r0) * lda + cg0 * 8;
  const u16* srcB = Bt + (size_t)(n0 + r0) * Kd + cg0 * 8;
  size_t rsB = (size_t)128 * Kd;

  int offB = swz16(wn * 64 + (lane & 15), lane >> 4) * 8;
  int offA = 32768 + swz16(wm * 64 + (lane & 15), lane >> 4) * 8;
  u16* ldsw = &lds[wv * 512];

  f32x4 acc[4][4] = {};
  B8 aR[4], bR[4];

  gll16(srcB,      ldsw +     0); gll16(srcB + rsB,      ldsw +  4096); gll16(srcA,      ldsw + 32768);
  gll16(srcB + 32, ldsw +  8192); gll16(srcB + 32 + rsB, ldsw + 12288); gll16(srcA + 32, ldsw + 36864);
  gll16(srcB + 64, ldsw + 16384); gll16(srcB + 64 + rsB, ldsw + 20480); gll16(srcA + 64, ldsw + 40960);
  asm volatile("s_waitcnt vmcnt(6)" ::: "memory");
  asm volatile("s_barrier" ::: "memory");

  const u16* stA = srcA + 64;
  const u16* stB = srcB + 64;

  auto rd = [&](int s) {
#pragma unroll
    for (int f = 0; f < 4; ++f) bR[f].u = *(const uint4*)&lds[offB + s * 8192 + f * 512];
#pragma unroll
    for (int f = 0; f < 4; ++f) aR[f].u = *(const uint4*)&lds[offA + s * 4096 + f * 512];
  };
  auto mfma16 = [&]() {
    asm volatile("s_barrier" ::: "memory");
    asm volatile("s_waitcnt lgkmcnt(0)" ::: "memory");
    __builtin_amdgcn_s_setprio(1);
#pragma unroll
    for (int nf = 0; nf < 4; ++nf)
#pragma unroll
      for (int mf = 0; mf < 4; ++mf)
        acc[mf][nf] = __builtin_amdgcn_mfma_f32_16x16x32_bf16(aR[mf].v, bR[nf].v, acc[mf][nf], 0, 0, 0);
    __builtin_amdgcn_s_setprio(0);
  };

  for (int ktp = 0; ktp < NT; ktp += 2) {
    bool sAll = (ktp < NT - 2);
    rd(0);
    { gll16(stB + 32, ldsw + 24576); gll16(stB + 32 + rsB, ldsw + 28672); gll16(stA + 32, ldsw + 45056); }
    mfma16();
    asm volatile("s_waitcnt vmcnt(6)" ::: "memory");
    asm volatile("s_barrier" ::: "memory");
    rd(1);
    if (sAll) { gll16(stB + 64, ldsw + 0); gll16(stB + 64 + rsB, ldsw + 4096); gll16(stA + 64, ldsw + 32768); }
    mfma16();
    if (sAll) asm volatile("s_waitcnt vmcnt(6)" ::: "memory");
    else asm volatile("s_waitcnt vmcnt(3)" ::: "memory");
    asm volatile("s_barrier" ::: "memory");
    rd(2);
    if (sAll) { gll16(stB + 96, ldsw + 8192); gll16(stB + 96 + rsB, ldsw + 12288); gll16(stA + 96, ldsw + 36864); }
    mfma16();
    if (sAll) asm volatile("s_waitcnt vmcnt(6)" ::: "memory");
    else asm volatile("s_waitcnt vmcnt(0)" ::: "memory");
    asm volatile("s_barrier" ::: "memory");
    rd(3);
    if (sAll) { gll16(stB + 128, ldsw + 16384); gll16(stB + 128 + rsB, ldsw + 20480); gll16(stA + 128, ldsw + 40960); }
    mfma16();
    if (sAll) asm volatile("s_waitcnt vmcnt(6)" ::: "memory");
    asm volatile("s_barrier" ::: "memory");
    stA += 128; stB += 128;
  }

#pragma unroll
  for (int mf = 0; mf < 4; ++mf) {
#pragma unroll
    for (int rr = 0; rr < 4; ++rr) {
      int row = m0 + wm * 64 + mf * 16 + (lane >> 4) * 4 + rr;
#pragma unroll
      for (int nf = 0; nf < 4; ++nf) {
        int col = n0 + wn * 64 + nf * 16 + (lane & 15);
        float v = acc[mf][nf][rr];
        if (EPI == 0) {
          Cb[(size_t)row * N + col] = f2b(v);
        } else if (EPI == 1) {
          int b = row >> 10;
          Cf[(size_t)row * Hh + col] = hid[((size_t)b * Ss + idx[row]) * Hh + col] + v;
        } else {
          int b = row >> 10;
          Cf[((size_t)b * Ss + idx[row]) * Hh + col] = hs2[(size_t)row * Hh + col] + v * scalev[b];
        }
      }
    }
  }
}

// ---------------- RoPE on fused QKV buffer (stride 6144) ----------------
__global__ __launch_bounds__(256) void rope_qk(u16* __restrict__ qkv,
                                               const int* __restrict__ posg) {
  int gid = blockIdx.x * 256 + threadIdx.x;
  int i = gid & 63;
  int h = (gid >> 6) & 15;
  int t = gid >> 10;
  float p = (float)posg[t];
  float inv = exp2f(-(float)i * (13.287712379549449f / 64.0f));
  float ang = p * inv;
  float sv, cv;
  sincosf(ang, &sv, &cv);
  size_t base = (size_t)t * 6144 + h * DHh + i;
  u16* Q = qkv;
  u16* Kq = qkv + 2048;
  float q1 = b2f(Q[base]), q2 = b2f(Q[base + 64]);
  Q[base] = f2b(q1 * cv - q2 * sv);
  Q[base + 64] = f2b(q2 * cv + q1 * sv);
  float k1 = b2f(Kq[base]), k2 = b2f(Kq[base + 64]);
  Kq[base] = f2b(k1 * cv - k2 * sv);
  Kq[base + 64] = f2b(k2 * cv + k1 * sv);
}

// ---------------- flash attention, KVBLK=64, mask-free fast path ----------------
__global__ __launch_bounds__(256) void attn_k(const u16* __restrict__ QKV, u16* __restrict__ O) {
  int qb = blockIdx.x;    // 16 q-tiles of 64
  int head = blockIdx.y;  // 64 = b*16+h
  int b = head >> 4, h = head & 15;
  int tid = threadIdx.x, lane = tid & 63, wv = tid >> 6;
  __shared__ __align__(16) u16 Ksm[64][136];
  __shared__ __align__(16) u16 Vs[128][72];   // V^T: [d][key]
  __shared__ __align__(16) u16 Ps[4][16][72];
  int q0 = qb * 64 + wv * 16;
  int tokQ = b * KS + q0;
  B8 qf[4];
  const u16* qp = QKV + (size_t)(tokQ + (lane & 15)) * 6144 + h * DHh;
#pragma unroll
  for (int c = 0; c < 4; ++c) qf[c].u = *(const uint4*)(qp + c * 32 + (lane >> 4) * 8);
  float m_run = -1e30f, l_run = 0.0f;
  f32x4 oacc[8] = {};
  int qi = q0 + (lane & 15);

  for (int ks = 0; ks <= qb * 64; ks += 64) {
    bool maskTile = (ks == qb * 64);  // only the diagonal tile needs causal masking
    __syncthreads();
#pragma unroll
    for (int it = 0; it < 4; ++it) {
      int s = it * 256 + tid;
      int key = s >> 4, d0 = (s & 15) * 8;
      size_t gb = (size_t)(b * KS + ks + key) * 6144 + 2048 + h * DHh + d0;
      uint4 kv = *(const uint4*)(QKV + gb);
      *(uint4*)&Ksm[key][d0] = kv;
      uint4 vv = *(const uint4*)(QKV + gb + 2048);
      u16* vp = (u16*)&vv;
#pragma unroll
      for (int j = 0; j < 8; ++j) Vs[d0 + j][key] = vp[j];
    }
    __syncthreads();
    // QK^T: st[kt] = S^T tile (rows=key 16kt.., cols=q)
    f32x4 st[4] = {};
#pragma unroll
    for (int c = 0; c < 4; ++c) {
      B8 kf;
#pragma unroll
      for (int kt = 0; kt < 4; ++kt) {
        kf.u = *(const uint4*)&Ksm[kt * 16 + (lane & 15)][c * 32 + (lane >> 4) * 8];
        st[kt] = __builtin_amdgcn_mfma_f32_16x16x32_bf16(kf.v, qf[c].v, st[kt], 0, 0, 0);
      }
    }
    float pmax = -INFINITY;
    if (maskTile) {
#pragma unroll
      for (int kt = 0; kt < 4; ++kt)
#pragma unroll
        for (int r = 0; r < 4; ++r) {
          int ki = ks + kt * 16 + (lane >> 4) * 4 + r;
          float v = st[kt][r] * 0.088388347648318447f;
          v = (ki <= qi) ? v : -INFINITY;
          st[kt][r] = v;
          pmax = fmaxf(pmax, v);
        }
    } else {
#pragma unroll
      for (int kt = 0; kt < 4; ++kt)
#pragma unroll
        for (int r = 0; r < 4; ++r) {
          float v = st[kt][r] * 0.088388347648318447f;
          st[kt][r] = v;
          pmax = fmaxf(pmax, v);
        }
    }
    pmax = fmaxf(pmax, __shfl_xor(pmax, 16));
    pmax = fmaxf(pmax, __shfl_xor(pmax, 32));
    float m_new = fmaxf(m_run, pmax);
    float alpha = __expf(m_run - m_new);
    float psum = 0.0f;
#pragma unroll
    for (int kt = 0; kt < 4; ++kt)
#pragma unroll
      for (int r = 0; r < 4; ++r) {
        float pv = __expf(st[kt][r] - m_new);
        st[kt][r] = pv;
        psum += pv;
      }
    psum += __shfl_xor(psum, 16);
    psum += __shfl_xor(psum, 32);
    l_run = l_run * alpha + psum;
    m_run = m_new;
#pragma unroll
    for (int kt = 0; kt < 4; ++kt) {
      ushort4 pk;
      pk.x = f2b(st[kt][0]); pk.y = f2b(st[kt][1]);
      pk.z = f2b(st[kt][2]); pk.w = f2b(st[kt][3]);
      *(ushort4*)&Ps[wv][lane & 15][kt * 16 + (lane >> 4) * 4] = pk;
    }
    B8 pf0, pf1;
    pf0.u = *(const uint4*)&Ps[wv][lane & 15][(lane >> 4) * 8];
    pf1.u = *(const uint4*)&Ps[wv][lane & 15][32 + (lane >> 4) * 8];
    float al0 = __shfl(alpha, (lane >> 4) * 4 + 0);
    float al1 = __shfl(alpha, (lane >> 4) * 4 + 1);
    float al2 = __shfl(alpha, (lane >> 4) * 4 + 2);
    float al3 = __shfl(alpha, (lane >> 4) * 4 + 3);
#pragma unroll
    for (int dt = 0; dt < 8; ++dt) {
      oacc[dt][0] *= al0; oacc[dt][1] *= al1;
      oacc[dt][2] *= al2; oacc[dt][3] *= al3;
    }
#pragma unroll
    for (int dt = 0; dt < 8; ++dt) {
      int d = dt * 16 + (lane & 15);
      B8 vf;
      vf.u = *(const uint4*)&Vs[d][(lane >> 4) * 8];
      oacc[dt] = __builtin_amdgcn_mfma_f32_16x16x32_bf16(pf0.v, vf.v, oacc[dt], 0, 0, 0);
      vf.u = *(const uint4*)&Vs[d][32 + (lane >> 4) * 8];
      oacc[dt] = __builtin_amdgcn_mfma_f32_16x16x32_bf16(pf1.v, vf.v, oacc[dt], 0, 0, 0);
    }
  }
  float linv = 1.0f / l_run;
  float li[4];
#pragma unroll
  for (int r = 0; r < 4; ++r) li[r] = __shfl(linv, (lane >> 4) * 4 + r);
#pragma unroll
  for (int r = 0; r < 4; ++r) {
    int tok = tokQ + (lane >> 4) * 4 + r;
    u16* op = O + (size_t)tok * Hh + h * DHh;
#pragma unroll
    for (int dt = 0; dt < 8; ++dt) op[dt * 16 + (lane & 15)] = f2b(oacc[dt][r] * li[r]);
  }
}

// ---------------- silu(g)*u on fused gate|up buffer (stride 16384) ----------------
__global__ __launch_bounds__(256) void silu_gu(u16* __restrict__ gu) {
  size_t gid = (size_t)blockIdx.x * 256 + threadIdx.x;
  size_t t = gid >> 10;
  int c = (int)(gid & 1023) * 8;
  u16* gp = gu + t * 16384 + c;
  const u16* upp = gp + 8192;
  B8 gv, uv;
  gv.u = *(const uint4*)gp;
  uv.u = *(const uint4*)upp;
#pragma unroll
  for (int j = 0; j < 8; ++j) {
    float x = b2f(gv.s[j]), y = b2f(uv.s[j]);
    gv.s[j] = f2b(x / (1.0f + __expf(-x)) * y);
  }
  *(uint4*)gp = gv.u;
}

extern "C" void kernel_launch(void* const* d_in, const int* in_sizes, int n_in,
                              void* d_out, int out_size, void* d_ws, size_t ws_size,
                              hipStream_t stream) {
  (void)in_sizes; (void)n_in; (void)out_size; (void)ws_size;
  const float* hid = (const float*)d_in[0];
  const int* posids = (const int*)d_in[1];
  const void* mask = d_in[2];
  const float* scores = (const float*)d_in[3];
  const float* Wq = (const float*)d_in[5];
  const float* Wk = (const float*)d_in[6];
  const float* Wv = (const float*)d_in[7];
  const float* Wo = (const float*)d_in[8];
  const float* Wg = (const float*)d_in[9];
  const float* Wu = (const float*)d_in[10];
  const float* Wd = (const float*)d_in[11];
  const float* ln1 = (const float*)d_in[12];
  const float* ln2 = (const float*)d_in[13];
  float* out = (float*)d_out;
  char* ws = (char*)d_ws;

  u16* WqkvT = (u16*)(ws + 0);            // [6144][2048] bf16
  u16* WoT   = (u16*)(ws + 25165824);     // [2048][2048]
  u16* WguT  = (u16*)(ws + 33554432);     // [16384][2048]
  u16* WdT   = (u16*)(ws + 100663296);    // [2048][8192]
  int* idx   = (int*)(ws + 134217728);
  int* posg  = (int*)(ws + 134217728 + 16384);
  float* scalev = (float*)(ws + 134217728 + 32768);
  char* R = ws + 134283264;               // 128MiB pool
  u16* hsn    = (u16*)(R);                // [4096][2048]
  u16* qkv    = (u16*)(R + 16777216);     // [4096][6144]
  u16* attn_o = (u16*)(R + 67108864);     // [4096][2048]
  u16* gu     = (u16*)(R);                // [4096][16384] overlays (dead by then)
  float* hs2  = (float*)(ws + 268500992); // [4096][2048] f32
  u16* mnorm  = (u16*)(ws + 302055424);   // [4096][2048]

  hipMemcpyAsync(out, hid, (size_t)Bb * Ss * Hh * 4, hipMemcpyDeviceToDevice, stream);

  topk_prep<<<Bb, 256, 0, stream>>>(mask, posids, scores, idx, posg, scalev);

  transpose_w<<<dim3(64, 64), dim3(32, 8), 0, stream>>>(Wq, WqkvT, 2048, 2048);
  transpose_w<<<dim3(64, 64), dim3(32, 8), 0, stream>>>(Wk, WqkvT + 2048 * 2048, 2048, 2048);
  transpose_w<<<dim3(64, 64), dim3(32, 8), 0, stream>>>(Wv, WqkvT + 4096 * 2048, 2048, 2048);
  transpose_w<<<dim3(64, 64), dim3(32, 8), 0, stream>>>(Wo, WoT, 2048, 2048);
  transpose_w<<<dim3(256, 64), dim3(32, 8), 0, stream>>>(Wg, WguT, 2048, 8192);
  transpose_w<<<dim3(256, 64), dim3(32, 8), 0, stream>>>(Wu, WguT + 8192 * 2048, 2048, 8192);
  transpose_w<<<dim3(64, 256), dim3(32, 8), 0, stream>>>(Wd, WdT, 8192, 2048);

  rmsnorm_k<1><<<NTOK, 256, 0, stream>>>(hid, idx, ln1, hsn);

  // QKV fused: gemm128 (gm=32, gw=3) 768 blocks
  gemm128<0><<<768, 512, 0, stream>>>(hsn, WqkvT, 6144, 2048, 2048, 32, 3, qkv,
                                      nullptr, nullptr, nullptr, nullptr, nullptr);

  rope_qk<<<16384, 256, 0, stream>>>(qkv, posg);

  attn_k<<<dim3(16, 64), 256, 0, stream>>>(qkv, attn_o);

  // Wo: gemm128 (gm=32, gw=1) 256 blocks
  gemm128<1><<<256, 512, 0, stream>>>(attn_o, WoT, 2048, 2048, 2048, 32, 1, nullptr,
                                      hid, idx, nullptr, nullptr, hs2);

  rmsnorm_k<0><<<NTOK, 256, 0, stream>>>(hs2, nullptr, ln2, mnorm);

  // gate|up fused: gemm256 (gm=16, gw=8) 1024 blocks
  gemm256<0><<<1024, 512, 0, stream>>>(mnorm, WguT, 16384, 2048, 2048, 16, 8, gu,
                                       nullptr, nullptr, nullptr, nullptr, nullptr);

  silu_gu<<<16384, 256, 0, stream>>>(gu);

  // down: gemm128 (gm=32, gw=1) 256 blocks
  gemm128<2><<<256, 512, 0, stream>>>(gu, WdT, 2048, 8192, 16384, 32, 1, nullptr,
                                      nullptr, idx, hs2, scalev, out);
}

// Round 8
// 1232.111 us; speedup vs baseline: 1.0279x; 1.0279x over previous
//
#include <hip/hip_runtime.h>
#include <hip/hip_bf16.h>
#include <stdint.h>

#define Bb 4
#define Ss 8192
#define Hh 2048
#define NHh 16
#define DHh 128
#define DFFf 8192
#define KS 1024
#define NTOK 4096

typedef unsigned short u16;
typedef __bf16 bf16x8 __attribute__((ext_vector_type(8)));
typedef float f32x4 __attribute__((ext_vector_type(4)));

union B8 { uint4 u; bf16x8 v; u16 s[8]; };

__device__ __forceinline__ float b2f(u16 x) { return __uint_as_float(((unsigned)x) << 16); }
__device__ __forceinline__ u16 f2b(float x) {
  __hip_bfloat16 h = __float2bfloat16(x);
  return *reinterpret_cast<u16*>(&h);
}

__device__ __forceinline__ void gll16(const void* g, void* l) {
  __builtin_amdgcn_global_load_lds((const __attribute__((address_space(1))) void*)g,
                                   (__attribute__((address_space(3))) void*)l, 16, 0, 0);
}

// swizzled 16B-unit index within a Rx32 bf16 region (row-pair XOR swizzle)
__device__ __forceinline__ int swz16(int r, int cg) {
  int u = ((r & 1) << 2) | cg;
  return ((r >> 1) << 3) | (u ^ ((r >> 1) & 7));
}

// ---------------- top-k index scan ----------------
__global__ void topk_prep(const void* maskp, const int* __restrict__ posids,
                          const float* __restrict__ scores,
                          int* __restrict__ idx, int* __restrict__ posg,
                          float* __restrict__ scalev) {
  int b = blockIdx.x;
  int tid = threadIdx.x, lane = tid & 63, wv = tid >> 6;
  __shared__ int wsum[4];
  __shared__ int base;
  __shared__ int mode;
  __shared__ int detCnt;
  if (tid == 0) { base = 0; detCnt = 0; }
  __syncthreads();
  {
    const unsigned char* mb = (const unsigned char*)maskp;
    int c = 0;
    for (int s = tid; s < 8192; s += 256) c += (mb[s] != 0);
    atomicAdd(&detCnt, c);
  }
  __syncthreads();
  if (tid == 0) mode = (detCnt == KS) ? 1 : 0;
  __syncthreads();
  const unsigned char* mb = (const unsigned char*)maskp;
  const int* mi = (const int*)maskp;
  for (int s0 = 0; s0 < Ss; s0 += 256) {
    int s = s0 + tid;
    int pred = mode ? (mb[(size_t)b * Ss + s] != 0) : (mi[(size_t)b * Ss + s] != 0);
    unsigned long long bal = __ballot(pred);
    int lp = __popcll(bal & ((1ull << lane) - 1ull));
    int wtot = __popcll(bal);
    if (lane == 0) wsum[wv] = wtot;
    __syncthreads();
    int woff = 0;
    for (int w = 0; w < wv; ++w) woff += wsum[w];
    int tot = wsum[0] + wsum[1] + wsum[2] + wsum[3];
    int p = base + woff + lp;
    if (pred && p < KS) {
      idx[b * KS + p] = s;
      posg[b * KS + p] = posids[(size_t)b * Ss + s];
    }
    __syncthreads();
    if (tid == 0) base += tot;
    __syncthreads();
  }
  if (b == 0 && tid < Bb) scalev[tid] = 0.5f * 1.0f + (scores[tid] - 0.5f) * 1.0f;
}

// ---------------- weight transpose fp32 -> bf16 ----------------
__global__ void transpose_w(const float* __restrict__ in, u16* __restrict__ out, int R, int C) {
  __shared__ float tile[32][33];
  int tx = threadIdx.x, ty = threadIdx.y;
  int c0 = blockIdx.x * 32, r0 = blockIdx.y * 32;
  for (int j = ty; j < 32; j += 8) tile[j][tx] = in[(size_t)(r0 + j) * C + c0 + tx];
  __syncthreads();
  for (int j = ty; j < 32; j += 8) out[(size_t)(c0 + j) * R + r0 + tx] = f2b(tile[tx][j]);
}

// ---------------- RMSNorm ----------------
template <int GATHER>
__global__ __launch_bounds__(256) void rmsnorm_k(const float* __restrict__ src0,
                                                 const int* __restrict__ idx,
                                                 const float* __restrict__ w,
                                                 u16* __restrict__ out) {
  int t = blockIdx.x;
  const float* src;
  if (GATHER) { int b = t >> 10; src = src0 + ((size_t)b * Ss + idx[t]) * Hh; }
  else src = src0 + (size_t)t * Hh;
  int tid = threadIdx.x, lane = tid & 63, wv = tid >> 6;
  float4 x0 = *(const float4*)(src + tid * 8);
  float4 x1 = *(const float4*)(src + tid * 8 + 4);
  float ss = x0.x * x0.x + x0.y * x0.y + x0.z * x0.z + x0.w * x0.w +
             x1.x * x1.x + x1.y * x1.y + x1.z * x1.z + x1.w * x1.w;
  for (int o = 32; o; o >>= 1) ss += __shfl_down(ss, o);
  __shared__ float wred[4];
  if (lane == 0) wred[wv] = ss;
  __syncthreads();
  float tot = wred[0] + wred[1] + wred[2] + wred[3];
  float r = rsqrtf(tot * (1.0f / Hh) + 1e-5f);
  const float* wp = w + tid * 8;
  u16* op = out + (size_t)t * Hh + tid * 8;
  float xs[8] = {x0.x, x0.y, x0.z, x0.w, x1.x, x1.y, x1.z, x1.w};
#pragma unroll
  for (int j = 0; j < 8; ++j) op[j] = f2b(xs[j] * r * wp[j]);
}

// ---------------- 256x256 8-phase bf16 GEMM, pair-unrolled, const offsets ----------------
template <int EPI>
__global__ __launch_bounds__(512, 2) void gemm256(
    const u16* __restrict__ A, const u16* __restrict__ Bt,
    int N, int Kd, int lda, int gm, int gw,
    u16* __restrict__ Cb,
    const float* __restrict__ hid, const int* __restrict__ idx,
    const float* __restrict__ hs2, const float* __restrict__ scalev,
    float* __restrict__ Cf) {
  __shared__ u16 lds[65536];
  int bid = blockIdx.x;
  int xcd = bid & 7;
  int i2 = bid >> 3;
  int bm = i2 / gw;             // bn-fast within XCD strip
  int bn = xcd * gw + i2 % gw;
  int m0 = bm * 256, n0 = bn * 256;
  int tid = threadIdx.x, lane = tid & 63, wv = tid >> 6;
  int wm = wv >> 2, wn = wv & 3;
  int NT = Kd >> 6;

  int P16 = wv * 64 + lane;
  int blk = P16 >> 3, up = P16 & 7;
  int uu = up ^ (blk & 7);
  int r0 = blk * 2 + (uu >> 2), cg0 = uu & 3;
  const u16* srcA = A + (size_t)(m0 + r0) * lda + cg0 * 8;
  const u16* srcB = Bt + (size_t)(n0 + r0) * Kd + cg0 * 8;
  size_t rsA = (size_t)128 * lda, rsB = (size_t)128 * Kd;

  int offA = swz16(wm * 128 + (lane & 15), lane >> 4) * 8;
  int offB = 32768 + swz16(wn * 64 + (lane & 15), lane >> 4) * 8;
  u16* ldsw = &lds[wv * 512];

  f32x4 acc[8][4] = {};
  B8 aR[4], bR[4];

  // prologue: 7 halves (t0 full, t1 minus A.kk1)
  gll16(srcB,      ldsw + 32768); gll16(srcB + rsB,      ldsw + 36864);
  gll16(srcA,      ldsw +     0); gll16(srcA + rsA,      ldsw +  4096);
  gll16(srcB + 32, ldsw + 40960); gll16(srcB + 32 + rsB, ldsw + 45056);
  gll16(srcA + 32, ldsw +  8192); gll16(srcA + 32 + rsA, ldsw + 12288);
  gll16(srcB + 64, ldsw + 49152); gll16(srcB + 64 + rsB, ldsw + 53248);
  gll16(srcA + 64, ldsw + 16384); gll16(srcA + 64 + rsA, ldsw + 20480);
  gll16(srcB + 96, ldsw + 57344); gll16(srcB + 96 + rsB, ldsw + 61440);
  asm volatile("s_waitcnt vmcnt(6)" ::: "memory");
  asm volatile("s_barrier" ::: "memory");

  const u16* stA = srcA + 64;
  const u16* stB = srcB + 64;

  auto phase = [&](int abase, int bbase, int mh) {
    if (mh == 0) {
#pragma unroll
      for (int nf = 0; nf < 4; ++nf) bR[nf].u = *(const uint4*)&lds[offB + bbase + nf * 512];
    }
#pragma unroll
    for (int i3 = 0; i3 < 4; ++i3)
      aR[i3].u = *(const uint4*)&lds[offA + abase + (i3 + 4 * mh) * 512];
  };
  auto mfma16 = [&](int mh) {
    asm volatile("s_barrier" ::: "memory");
    asm volatile("s_waitcnt lgkmcnt(0)" ::: "memory");
    __builtin_amdgcn_s_setprio(1);
#pragma unroll
    for (int nf = 0; nf < 4; ++nf)
#pragma unroll
      for (int i3 = 0; i3 < 4; ++i3)
        acc[mh * 4 + i3][nf] =
            __builtin_amdgcn_mfma_f32_16x16x32_bf16(aR[i3].v, bR[nf].v, acc[mh * 4 + i3][nf], 0, 0, 0);
    __builtin_amdgcn_s_setprio(0);
  };

  for (int ktp = 0; ktp < NT; ktp += 2) {
    bool sAll = (ktp < NT - 2);
    // ===== even body (d=0) =====
    phase(0, 0, 0);
    { gll16(stA + 32, ldsw + 24576); gll16(stA + 32 + rsA, ldsw + 28672); }
    mfma16(0);
    asm volatile("s_barrier" ::: "memory");
    phase(0, 0, 1);
    if (sAll) { gll16(stB + 64, ldsw + 32768); gll16(stB + 64 + rsB, ldsw + 36864); }
    mfma16(1);
    asm volatile("s_barrier" ::: "memory");
    phase(8192, 8192, 0);
    if (sAll) { gll16(stA + 64, ldsw + 0); gll16(stA + 64 + rsA, ldsw + 4096); }
    mfma16(0);
    asm volatile("s_barrier" ::: "memory");
    phase(8192, 8192, 1);
    if (sAll) { gll16(stB + 96, ldsw + 40960); gll16(stB + 96 + rsB, ldsw + 45056); }
    mfma16(1);
    if (sAll) asm volatile("s_waitcnt vmcnt(6)" ::: "memory");
    else asm volatile("s_waitcnt vmcnt(0)" ::: "memory");
    asm volatile("s_barrier" ::: "memory");
    // ===== odd body (d=1) =====
    phase(16384, 16384, 0);
    if (sAll) { gll16(stA + 96, ldsw + 8192); gll16(stA + 96 + rsA, ldsw + 12288); }
    mfma16(0);
    asm volatile("s_barrier" ::: "memory");
    phase(16384, 16384, 1);
    if (sAll) { gll16(stB + 128, ldsw + 49152); gll16(stB + 128 + rsB, ldsw + 53248); }
    mfma16(1);
    asm volatile("s_barrier" ::: "memory");
    phase(24576, 24576, 0);
    if (sAll) { gll16(stA + 128, ldsw + 16384); gll16(stA + 128 + rsA, ldsw + 20480); }
    mfma16(0);
    asm volatile("s_barrier" ::: "memory");
    phase(24576, 24576, 1);
    if (sAll) { gll16(stB + 160, ldsw + 57344); gll16(stB + 160 + rsB, ldsw + 61440); }
    mfma16(1);
    if (sAll) asm volatile("s_waitcnt vmcnt(6)" ::: "memory");
    asm volatile("s_barrier" ::: "memory");
    stA += 128; stB += 128;
  }

#pragma unroll
  for (int mf = 0; mf < 8; ++mf) {
#pragma unroll
    for (int rr = 0; rr < 4; ++rr) {
      int row = m0 + wm * 128 + mf * 16 + (lane >> 4) * 4 + rr;
#pragma unroll
      for (int nf = 0; nf < 4; ++nf) {
        int col = n0 + wn * 64 + nf * 16 + (lane & 15);
        float v = acc[mf][nf][rr];
        if (EPI == 0) {
          Cb[(size_t)row * N + col] = f2b(v);
        } else if (EPI == 1) {
          int b = row >> 10;
          Cf[(size_t)row * Hh + col] = hid[((size_t)b * Ss + idx[row]) * Hh + col] + v;
        } else {
          int b = row >> 10;
          Cf[((size_t)b * Ss + idx[row]) * Hh + col] = hs2[(size_t)row * Hh + col] + v * scalev[b];
        }
      }
    }
  }
}

// ---------------- 128x256 bf16 GEMM, 4-slot pipeline, pair-unrolled ----------------
template <int EPI>
__global__ __launch_bounds__(512, 2) void gemm128(
    const u16* __restrict__ A, const u16* __restrict__ Bt,
    int N, int Kd, int lda, int gm, int gw,
    u16* __restrict__ Cb,
    const float* __restrict__ hid, const int* __restrict__ idx,
    const float* __restrict__ hs2, const float* __restrict__ scalev,
    float* __restrict__ Cf) {
  __shared__ u16 lds[49152];
  int bid = blockIdx.x;
  int xcd = bid & 7;
  int i2 = bid >> 3;
  int bm = i2 / gw;
  int bn = xcd * gw + i2 % gw;
  int m0 = bm * 128, n0 = bn * 256;
  int tid = threadIdx.x, lane = tid & 63, wv = tid >> 6;
  int wm = wv >> 2, wn = wv & 3;
  int NT = Kd >> 6;

  int P16 = wv * 64 + lane;
  int blk = P16 >> 3, up = P16 & 7;
  int uu = up ^ (blk & 7);
  int r0 = blk * 2 + (uu >> 2), cg0 = uu & 3;
  const u16* srcA = A + (size_t)(m0 + r0) * lda + cg0 * 8;
  const u16* srcB = Bt + (size_t)(n0 + r0) * Kd + cg0 * 8;
  size_t rsB = (size_t)128 * Kd;

  int offB = swz16(wn * 64 + (lane & 15), lane >> 4) * 8;
  int offA = 32768 + swz16(wm * 64 + (lane & 15), lane >> 4) * 8;
  u16* ldsw = &lds[wv * 512];

  f32x4 acc[4][4] = {};
  B8 aR[4], bR[4];

  gll16(srcB,      ldsw +     0); gll16(srcB + rsB,      ldsw +  4096); gll16(srcA,      ldsw + 32768);
  gll16(srcB + 32, ldsw +  8192); gll16(srcB + 32 + rsB, ldsw + 12288); gll16(srcA + 32, ldsw + 36864);
  gll16(srcB + 64, ldsw + 16384); gll16(srcB + 64 + rsB, ldsw + 20480); gll16(srcA + 64, ldsw + 40960);
  asm volatile("s_waitcnt vmcnt(6)" ::: "memory");
  asm volatile("s_barrier" ::: "memory");

  const u16* stA = srcA + 64;
  const u16* stB = srcB + 64;

  auto rd = [&](int s) {
#pragma unroll
    for (int f = 0; f < 4; ++f) bR[f].u = *(const uint4*)&lds[offB + s * 8192 + f * 512];
#pragma unroll
    for (int f = 0; f < 4; ++f) aR[f].u = *(const uint4*)&lds[offA + s * 4096 + f * 512];
  };
  auto mfma16 = [&]() {
    asm volatile("s_barrier" ::: "memory");
    asm volatile("s_waitcnt lgkmcnt(0)" ::: "memory");
    __builtin_amdgcn_s_setprio(1);
#pragma unroll
    for (int nf = 0; nf < 4; ++nf)
#pragma unroll
      for (int mf = 0; mf < 4; ++mf)
        acc[mf][nf] = __builtin_amdgcn_mfma_f32_16x16x32_bf16(aR[mf].v, bR[nf].v, acc[mf][nf], 0, 0, 0);
    __builtin_amdgcn_s_setprio(0);
  };

  for (int ktp = 0; ktp < NT; ktp += 2) {
    bool sAll = (ktp < NT - 2);
    rd(0);
    { gll16(stB + 32, ldsw + 24576); gll16(stB + 32 + rsB, ldsw + 28672); gll16(stA + 32, ldsw + 45056); }
    mfma16();
    asm volatile("s_waitcnt vmcnt(6)" ::: "memory");
    asm volatile("s_barrier" ::: "memory");
    rd(1);
    if (sAll) { gll16(stB + 64, ldsw + 0); gll16(stB + 64 + rsB, ldsw + 4096); gll16(stA + 64, ldsw + 32768); }
    mfma16();
    if (sAll) asm volatile("s_waitcnt vmcnt(6)" ::: "memory");
    else asm volatile("s_waitcnt vmcnt(3)" ::: "memory");
    asm volatile("s_barrier" ::: "memory");
    rd(2);
    if (sAll) { gll16(stB + 96, ldsw + 8192); gll16(stB + 96 + rsB, ldsw + 12288); gll16(stA + 96, ldsw + 36864); }
    mfma16();
    if (sAll) asm volatile("s_waitcnt vmcnt(6)" ::: "memory");
    else asm volatile("s_waitcnt vmcnt(0)" ::: "memory");
    asm volatile("s_barrier" ::: "memory");
    rd(3);
    if (sAll) { gll16(stB + 128, ldsw + 16384); gll16(stB + 128 + rsB, ldsw + 20480); gll16(stA + 128, ldsw + 40960); }
    mfma16();
    if (sAll) asm volatile("s_waitcnt vmcnt(6)" ::: "memory");
    asm volatile("s_barrier" ::: "memory");
    stA += 128; stB += 128;
  }

#pragma unroll
  for (int mf = 0; mf < 4; ++mf) {
#pragma unroll
    for (int rr = 0; rr < 4; ++rr) {
      int row = m0 + wm * 64 + mf * 16 + (lane >> 4) * 4 + rr;
#pragma unroll
      for (int nf = 0; nf < 4; ++nf) {
        int col = n0 + wn * 64 + nf * 16 + (lane & 15);
        float v = acc[mf][nf][rr];
        if (EPI == 0) {
          Cb[(size_t)row * N + col] = f2b(v);
        } else if (EPI == 1) {
          int b = row >> 10;
          Cf[(size_t)row * Hh + col] = hid[((size_t)b * Ss + idx[row]) * Hh + col] + v;
        } else {
          int b = row >> 10;
          Cf[((size_t)b * Ss + idx[row]) * Hh + col] = hs2[(size_t)row * Hh + col] + v * scalev[b];
        }
      }
    }
  }
}

// ---------------- RoPE on fused QKV buffer (stride 6144) ----------------
__global__ __launch_bounds__(256) void rope_qk(u16* __restrict__ qkv,
                                               const int* __restrict__ posg) {
  int gid = blockIdx.x * 256 + threadIdx.x;
  int i = gid & 63;
  int h = (gid >> 6) & 15;
  int t = gid >> 10;
  float p = (float)posg[t];
  float inv = exp2f(-(float)i * (13.287712379549449f / 64.0f));
  float ang = p * inv;
  float sv, cv;
  sincosf(ang, &sv, &cv);
  size_t base = (size_t)t * 6144 + h * DHh + i;
  u16* Q = qkv;
  u16* Kq = qkv + 2048;
  float q1 = b2f(Q[base]), q2 = b2f(Q[base + 64]);
  Q[base] = f2b(q1 * cv - q2 * sv);
  Q[base + 64] = f2b(q2 * cv + q1 * sv);
  float k1 = b2f(Kq[base]), k2 = b2f(Kq[base + 64]);
  Kq[base] = f2b(k1 * cv - k2 * sv);
  Kq[base + 64] = f2b(k2 * cv + k1 * sv);
}

// ---------------- flash attention, KVBLK=64, Ps aliased into Ksm, V-write swizzle ----------------
// LDS = Ksm 17408 + Vs 18432 = 35840 B -> 4 blocks/CU (grid 1024 = 4x256 exactly resident).
__global__ __launch_bounds__(256) void attn_k(const u16* __restrict__ QKV, u16* __restrict__ O) {
  int qb = blockIdx.x;    // 16 q-tiles of 64
  int head = blockIdx.y;  // 64 = b*16+h
  int b = head >> 4, h = head & 15;
  int tid = threadIdx.x, lane = tid & 63, wv = tid >> 6;
  __shared__ __align__(16) u16 Ksm[64][136];
  __shared__ __align__(16) u16 Vs[128][72];   // V^T: [d][swizzled key]
  u16* PsB = &Ksm[0][0] + wv * 1152;          // per-wave P bounce, aliases Ksm (dead after QK reads)
  int q0 = qb * 64 + wv * 16;
  int tokQ = b * KS + q0;
  B8 qf[4];
  const u16* qp = QKV + (size_t)(tokQ + (lane & 15)) * 6144 + h * DHh;
#pragma unroll
  for (int c = 0; c < 4; ++c) qf[c].u = *(const uint4*)(qp + c * 32 + (lane >> 4) * 8);
  float m_run = -1e30f, l_run = 0.0f;
  f32x4 oacc[8] = {};
  int qi = q0 + (lane & 15);

  for (int ks = 0; ks <= qb * 64; ks += 64) {
    bool maskTile = (ks == qb * 64);  // only the diagonal tile needs causal masking
    __syncthreads();
#pragma unroll
    for (int it = 0; it < 4; ++it) {
      int s = it * 256 + tid;
      int key = s >> 4, d0 = (s & 15) * 8;
      size_t gb = (size_t)(b * KS + ks + key) * 6144 + 2048 + h * DHh + d0;
      uint4 kv = *(const uint4*)(QKV + gb);
      *(uint4*)&Ksm[key][d0] = kv;
      uint4 vv = *(const uint4*)(QKV + gb + 2048);
      u16* vp = (u16*)&vv;
      int colg = ((key >> 3) ^ ((d0 >> 3) & 7)) << 3;
      int col = colg | (key & 7);
#pragma unroll
      for (int j = 0; j < 8; ++j) Vs[d0 + j][col] = vp[j];
    }
    __syncthreads();
    // QK^T: st[kt] = S^T tile (rows=key 16kt.., cols=q)
    f32x4 st[4] = {};
#pragma unroll
    for (int c = 0; c < 4; ++c) {
      B8 kf;
#pragma unroll
      for (int kt = 0; kt < 4; ++kt) {
        kf.u = *(const uint4*)&Ksm[kt * 16 + (lane & 15)][c * 32 + (lane >> 4) * 8];
        st[kt] = __builtin_amdgcn_mfma_f32_16x16x32_bf16(kf.v, qf[c].v, st[kt], 0, 0, 0);
      }
    }
    __syncthreads();  // all waves' Ksm reads done; Ps region (aliases Ksm) now writable
    float pmax = -INFINITY;
    if (maskTile) {
#pragma unroll
      for (int kt = 0; kt < 4; ++kt)
#pragma unroll
        for (int r = 0; r < 4; ++r) {
          int ki = ks + kt * 16 + (lane >> 4) * 4 + r;
          float v = st[kt][r] * 0.088388347648318447f;
          v = (ki <= qi) ? v : -INFINITY;
          st[kt][r] = v;
          pmax = fmaxf(pmax, v);
        }
    } else {
#pragma unroll
      for (int kt = 0; kt < 4; ++kt)
#pragma unroll
        for (int r = 0; r < 4; ++r) {
          float v = st[kt][r] * 0.088388347648318447f;
          st[kt][r] = v;
          pmax = fmaxf(pmax, v);
        }
    }
    pmax = fmaxf(pmax, __shfl_xor(pmax, 16));
    pmax = fmaxf(pmax, __shfl_xor(pmax, 32));
    float m_new = fmaxf(m_run, pmax);
    float alpha = __expf(m_run - m_new);
    float psum = 0.0f;
#pragma unroll
    for (int kt = 0; kt < 4; ++kt)
#pragma unroll
      for (int r = 0; r < 4; ++r) {
        float pv = __expf(st[kt][r] - m_new);
        st[kt][r] = pv;
        psum += pv;
      }
    psum += __shfl_xor(psum, 16);
    psum += __shfl_xor(psum, 32);
    l_run = l_run * alpha + psum;
    m_run = m_new;
#pragma unroll
    for (int kt = 0; kt < 4; ++kt) {
      ushort4 pk;
      pk.x = f2b(st[kt][0]); pk.y = f2b(st[kt][1]);
      pk.z = f2b(st[kt][2]); pk.w = f2b(st[kt][3]);
      *(ushort4*)&PsB[(lane & 15) * 72 + kt * 16 + (lane >> 4) * 4] = pk;
    }
    B8 pf0, pf1;
    pf0.u = *(const uint4*)&PsB[(lane & 15) * 72 + (lane >> 4) * 8];
    pf1.u = *(const uint4*)&PsB[(lane & 15) * 72 + 32 + (lane >> 4) * 8];
    float al0 = __shfl(alpha, (lane >> 4) * 4 + 0);
    float al1 = __shfl(alpha, (lane >> 4) * 4 + 1);
    float al2 = __shfl(alpha, (lane >> 4) * 4 + 2);
    float al3 = __shfl(alpha, (lane >> 4) * 4 + 3);
#pragma unroll
    for (int dt = 0; dt < 8; ++dt) {
      oacc[dt][0] *= al0; oacc[dt][1] *= al1;
      oacc[dt][2] *= al2; oacc[dt][3] *= al3;
    }
#pragma unroll
    for (int dt = 0; dt < 8; ++dt) {
      int d = dt * 16 + (lane & 15);
      int g = (d >> 3) & 7;
      B8 vf;
      vf.u = *(const uint4*)&Vs[d][(((lane >> 4) ^ g) << 3)];
      oacc[dt] = __builtin_amdgcn_mfma_f32_16x16x32_bf16(pf0.v, vf.v, oacc[dt], 0, 0, 0);
      vf.u = *(const uint4*)&Vs[d][(((4 + (lane >> 4)) ^ g) << 3)];
      oacc[dt] = __builtin_amdgcn_mfma_f32_16x16x32_bf16(pf1.v, vf.v, oacc[dt], 0, 0, 0);
    }
  }
  float linv = 1.0f / l_run;
  float li[4];
#pragma unroll
  for (int r = 0; r < 4; ++r) li[r] = __shfl(linv, (lane >> 4) * 4 + r);
#pragma unroll
  for (int r = 0; r < 4; ++r) {
    int tok = tokQ + (lane >> 4) * 4 + r;
    u16* op = O + (size_t)tok * Hh + h * DHh;
#pragma unroll
    for (int dt = 0; dt < 8; ++dt) op[dt * 16 + (lane & 15)] = f2b(oacc[dt][r] * li[r]);
  }
}

// ---------------- silu(g)*u on fused gate|up buffer (stride 16384) ----------------
__global__ __launch_bounds__(256) void silu_gu(u16* __restrict__ gu) {
  size_t gid = (size_t)blockIdx.x * 256 + threadIdx.x;
  size_t t = gid >> 10;
  int c = (int)(gid & 1023) * 8;
  u16* gp = gu + t * 16384 + c;
  const u16* upp = gp + 8192;
  B8 gv, uv;
  gv.u = *(const uint4*)gp;
  uv.u = *(const uint4*)upp;
#pragma unroll
  for (int j = 0; j < 8; ++j) {
    float x = b2f(gv.s[j]), y = b2f(uv.s[j]);
    gv.s[j] = f2b(x / (1.0f + __expf(-x)) * y);
  }
  *(uint4*)gp = gv.u;
}

extern "C" void kernel_launch(void* const* d_in, const int* in_sizes, int n_in,
                              void* d_out, int out_size, void* d_ws, size_t ws_size,
                              hipStream_t stream) {
  (void)in_sizes; (void)n_in; (void)out_size; (void)ws_size;
  const float* hid = (const float*)d_in[0];
  const int* posids = (const int*)d_in[1];
  const void* mask = d_in[2];
  const float* scores = (const float*)d_in[3];
  const float* Wq = (const float*)d_in[5];
  const float* Wk = (const float*)d_in[6];
  const float* Wv = (const float*)d_in[7];
  const float* Wo = (const float*)d_in[8];
  const float* Wg = (const float*)d_in[9];
  const float* Wu = (const float*)d_in[10];
  const float* Wd = (const float*)d_in[11];
  const float* ln1 = (const float*)d_in[12];
  const float* ln2 = (const float*)d_in[13];
  float* out = (float*)d_out;
  char* ws = (char*)d_ws;

  u16* WqkvT = (u16*)(ws + 0);            // [6144][2048] bf16
  u16* WoT   = (u16*)(ws + 25165824);     // [2048][2048]
  u16* WguT  = (u16*)(ws + 33554432);     // [16384][2048]
  u16* WdT   = (u16*)(ws + 100663296);    // [2048][8192]
  int* idx   = (int*)(ws + 134217728);
  int* posg  = (int*)(ws + 134217728 + 16384);
  float* scalev = (float*)(ws + 134217728 + 32768);
  char* R = ws + 134283264;               // 128MiB pool
  u16* hsn    = (u16*)(R);                // [4096][2048]
  u16* qkv    = (u16*)(R + 16777216);     // [4096][6144]
  u16* attn_o = (u16*)(R + 67108864);     // [4096][2048]
  u16* gu     = (u16*)(R);                // [4096][16384] overlays (dead by then)
  float* hs2  = (float*)(ws + 268500992); // [4096][2048] f32
  u16* mnorm  = (u16*)(ws + 302055424);   // [4096][2048]

  hipMemcpyAsync(out, hid, (size_t)Bb * Ss * Hh * 4, hipMemcpyDeviceToDevice, stream);

  topk_prep<<<Bb, 256, 0, stream>>>(mask, posids, scores, idx, posg, scalev);

  transpose_w<<<dim3(64, 64), dim3(32, 8), 0, stream>>>(Wq, WqkvT, 2048, 2048);
  transpose_w<<<dim3(64, 64), dim3(32, 8), 0, stream>>>(Wk, WqkvT + 2048 * 2048, 2048, 2048);
  transpose_w<<<dim3(64, 64), dim3(32, 8), 0, stream>>>(Wv, WqkvT + 4096 * 2048, 2048, 2048);
  transpose_w<<<dim3(64, 64), dim3(32, 8), 0, stream>>>(Wo, WoT, 2048, 2048);
  transpose_w<<<dim3(256, 64), dim3(32, 8), 0, stream>>>(Wg, WguT, 2048, 8192);
  transpose_w<<<dim3(256, 64), dim3(32, 8), 0, stream>>>(Wu, WguT + 8192 * 2048, 2048, 8192);
  transpose_w<<<dim3(64, 256), dim3(32, 8), 0, stream>>>(Wd, WdT, 8192, 2048);

  rmsnorm_k<1><<<NTOK, 256, 0, stream>>>(hid, idx, ln1, hsn);

  // QKV fused: gemm128 (gm=32, gw=3) 768 blocks
  gemm128<0><<<768, 512, 0, stream>>>(hsn, WqkvT, 6144, 2048, 2048, 32, 3, qkv,
                                      nullptr, nullptr, nullptr, nullptr, nullptr);

  rope_qk<<<16384, 256, 0, stream>>>(qkv, posg);

  attn_k<<<dim3(16, 64), 256, 0, stream>>>(qkv, attn_o);

  // Wo: gemm128 (gm=32, gw=1) 256 blocks
  gemm128<1><<<256, 512, 0, stream>>>(attn_o, WoT, 2048, 2048, 2048, 32, 1, nullptr,
                                      hid, idx, nullptr, nullptr, hs2);

  rmsnorm_k<0><<<NTOK, 256, 0, stream>>>(hs2, nullptr, ln2, mnorm);

  // gate|up fused: gemm256 (gm=16, gw=8) 1024 blocks
  gemm256<0><<<1024, 512, 0, stream>>>(mnorm, WguT, 16384, 2048, 2048, 16, 8, gu,
                                       nullptr, nullptr, nullptr, nullptr, nullptr);

  silu_gu<<<16384, 256, 0, stream>>>(gu);

  // down: gemm128 (gm=32, gw=1) 256 blocks
  gemm128<2><<<256, 512, 0, stream>>>(gu, WdT, 2048, 8192, 16384, 32, 1, nullptr,
                                      nullptr, idx, hs2, scalev, out);
}

// Round 9
// 1178.447 us; speedup vs baseline: 1.0748x; 1.0455x over previous
//
#include <hip/hip_runtime.h>
#include <hip/hip_bf16.h>
#include <stdint.h>

#define Bb 4
#define Ss 8192
#define Hh 2048
#define NHh 16
#define DHh 128
#define DFFf 8192
#define KS 1024
#define NTOK 4096

typedef unsigned short u16;
typedef __bf16 bf16x8 __attribute__((ext_vector_type(8)));
typedef float f32x4 __attribute__((ext_vector_type(4)));

union B8 { uint4 u; bf16x8 v; u16 s[8]; };

__device__ __forceinline__ float b2f(u16 x) { return __uint_as_float(((unsigned)x) << 16); }
__device__ __forceinline__ u16 f2b(float x) {
  __hip_bfloat16 h = __float2bfloat16(x);
  return *reinterpret_cast<u16*>(&h);
}

__device__ __forceinline__ void gll16(const void* g, void* l) {
  __builtin_amdgcn_global_load_lds((const __attribute__((address_space(1))) void*)g,
                                   (__attribute__((address_space(3))) void*)l, 16, 0, 0);
}

// swizzled 16B-unit index within a Rx32 bf16 region (row-pair XOR swizzle)
__device__ __forceinline__ int swz16(int r, int cg) {
  int u = ((r & 1) << 2) | cg;
  return ((r >> 1) << 3) | (u ^ ((r >> 1) & 7));
}

// ---------------- top-k index scan ----------------
__global__ void topk_prep(const void* maskp, const int* __restrict__ posids,
                          const float* __restrict__ scores,
                          int* __restrict__ idx, int* __restrict__ posg,
                          float* __restrict__ scalev) {
  int b = blockIdx.x;
  int tid = threadIdx.x, lane = tid & 63, wv = tid >> 6;
  __shared__ int wsum[4];
  __shared__ int base;
  __shared__ int mode;
  __shared__ int detCnt;
  if (tid == 0) { base = 0; detCnt = 0; }
  __syncthreads();
  {
    const unsigned char* mb = (const unsigned char*)maskp;
    int c = 0;
    for (int s = tid; s < 8192; s += 256) c += (mb[s] != 0);
    atomicAdd(&detCnt, c);
  }
  __syncthreads();
  if (tid == 0) mode = (detCnt == KS) ? 1 : 0;
  __syncthreads();
  const unsigned char* mb = (const unsigned char*)maskp;
  const int* mi = (const int*)maskp;
  for (int s0 = 0; s0 < Ss; s0 += 256) {
    int s = s0 + tid;
    int pred = mode ? (mb[(size_t)b * Ss + s] != 0) : (mi[(size_t)b * Ss + s] != 0);
    unsigned long long bal = __ballot(pred);
    int lp = __popcll(bal & ((1ull << lane) - 1ull));
    int wtot = __popcll(bal);
    if (lane == 0) wsum[wv] = wtot;
    __syncthreads();
    int woff = 0;
    for (int w = 0; w < wv; ++w) woff += wsum[w];
    int tot = wsum[0] + wsum[1] + wsum[2] + wsum[3];
    int p = base + woff + lp;
    if (pred && p < KS) {
      idx[b * KS + p] = s;
      posg[b * KS + p] = posids[(size_t)b * Ss + s];
    }
    __syncthreads();
    if (tid == 0) base += tot;
    __syncthreads();
  }
  if (b == 0 && tid < Bb) scalev[tid] = 0.5f * 1.0f + (scores[tid] - 0.5f) * 1.0f;
}

// ---------------- weight transpose fp32 -> bf16 ----------------
__global__ void transpose_w(const float* __restrict__ in, u16* __restrict__ out, int R, int C) {
  __shared__ float tile[32][33];
  int tx = threadIdx.x, ty = threadIdx.y;
  int c0 = blockIdx.x * 32, r0 = blockIdx.y * 32;
  for (int j = ty; j < 32; j += 8) tile[j][tx] = in[(size_t)(r0 + j) * C + c0 + tx];
  __syncthreads();
  for (int j = ty; j < 32; j += 8) out[(size_t)(c0 + j) * R + r0 + tx] = f2b(tile[tx][j]);
}

// ---------------- RMSNorm ----------------
template <int GATHER>
__global__ __launch_bounds__(256) void rmsnorm_k(const float* __restrict__ src0,
                                                 const int* __restrict__ idx,
                                                 const float* __restrict__ w,
                                                 u16* __restrict__ out) {
  int t = blockIdx.x;
  const float* src;
  if (GATHER) { int b = t >> 10; src = src0 + ((size_t)b * Ss + idx[t]) * Hh; }
  else src = src0 + (size_t)t * Hh;
  int tid = threadIdx.x, lane = tid & 63, wv = tid >> 6;
  float4 x0 = *(const float4*)(src + tid * 8);
  float4 x1 = *(const float4*)(src + tid * 8 + 4);
  float ss = x0.x * x0.x + x0.y * x0.y + x0.z * x0.z + x0.w * x0.w +
             x1.x * x1.x + x1.y * x1.y + x1.z * x1.z + x1.w * x1.w;
  for (int o = 32; o; o >>= 1) ss += __shfl_down(ss, o);
  __shared__ float wred[4];
  if (lane == 0) wred[wv] = ss;
  __syncthreads();
  float tot = wred[0] + wred[1] + wred[2] + wred[3];
  float r = rsqrtf(tot * (1.0f / Hh) + 1e-5f);
  const float* wp = w + tid * 8;
  u16* op = out + (size_t)t * Hh + tid * 8;
  float xs[8] = {x0.x, x0.y, x0.z, x0.w, x1.x, x1.y, x1.z, x1.w};
#pragma unroll
  for (int j = 0; j < 8; ++j) op[j] = f2b(xs[j] * r * wp[j]);
}

// ---------------- 256x256 8-phase bf16 GEMM, pair-unrolled, const offsets ----------------
template <int EPI>
__global__ __launch_bounds__(512, 2) void gemm256(
    const u16* __restrict__ A, const u16* __restrict__ Bt,
    int N, int Kd, int lda, int gm, int gw,
    u16* __restrict__ Cb,
    const float* __restrict__ hid, const int* __restrict__ idx,
    const float* __restrict__ hs2, const float* __restrict__ scalev,
    float* __restrict__ Cf) {
  __shared__ u16 lds[65536];
  int bid = blockIdx.x;
  int xcd = bid & 7;
  int i2 = bid >> 3;
  int bm = i2 / gw;             // bn-fast within XCD strip
  int bn = xcd * gw + i2 % gw;
  int m0 = bm * 256, n0 = bn * 256;
  int tid = threadIdx.x, lane = tid & 63, wv = tid >> 6;
  int wm = wv >> 2, wn = wv & 3;
  int NT = Kd >> 6;

  int P16 = wv * 64 + lane;
  int blk = P16 >> 3, up = P16 & 7;
  int uu = up ^ (blk & 7);
  int r0 = blk * 2 + (uu >> 2), cg0 = uu & 3;
  const u16* srcA = A + (size_t)(m0 + r0) * lda + cg0 * 8;
  const u16* srcB = Bt + (size_t)(n0 + r0) * Kd + cg0 * 8;
  size_t rsA = (size_t)128 * lda, rsB = (size_t)128 * Kd;

  int offA = swz16(wm * 128 + (lane & 15), lane >> 4) * 8;
  int offB = 32768 + swz16(wn * 64 + (lane & 15), lane >> 4) * 8;
  u16* ldsw = &lds[wv * 512];

  f32x4 acc[8][4] = {};
  B8 aR[4], bR[4];

  // prologue: 7 halves (t0 full, t1 minus A.kk1)
  gll16(srcB,      ldsw + 32768); gll16(srcB + rsB,      ldsw + 36864);
  gll16(srcA,      ldsw +     0); gll16(srcA + rsA,      ldsw +  4096);
  gll16(srcB + 32, ldsw + 40960); gll16(srcB + 32 + rsB, ldsw + 45056);
  gll16(srcA + 32, ldsw +  8192); gll16(srcA + 32 + rsA, ldsw + 12288);
  gll16(srcB + 64, ldsw + 49152); gll16(srcB + 64 + rsB, ldsw + 53248);
  gll16(srcA + 64, ldsw + 16384); gll16(srcA + 64 + rsA, ldsw + 20480);
  gll16(srcB + 96, ldsw + 57344); gll16(srcB + 96 + rsB, ldsw + 61440);
  asm volatile("s_waitcnt vmcnt(6)" ::: "memory");
  asm volatile("s_barrier" ::: "memory");

  const u16* stA = srcA + 64;
  const u16* stB = srcB + 64;

  auto phase = [&](int abase, int bbase, int mh) {
    if (mh == 0) {
#pragma unroll
      for (int nf = 0; nf < 4; ++nf) bR[nf].u = *(const uint4*)&lds[offB + bbase + nf * 512];
    }
#pragma unroll
    for (int i3 = 0; i3 < 4; ++i3)
      aR[i3].u = *(const uint4*)&lds[offA + abase + (i3 + 4 * mh) * 512];
  };
  auto mfma16 = [&](int mh) {
    asm volatile("s_barrier" ::: "memory");
    asm volatile("s_waitcnt lgkmcnt(0)" ::: "memory");
    __builtin_amdgcn_s_setprio(1);
#pragma unroll
    for (int nf = 0; nf < 4; ++nf)
#pragma unroll
      for (int i3 = 0; i3 < 4; ++i3)
        acc[mh * 4 + i3][nf] =
            __builtin_amdgcn_mfma_f32_16x16x32_bf16(aR[i3].v, bR[nf].v, acc[mh * 4 + i3][nf], 0, 0, 0);
    __builtin_amdgcn_s_setprio(0);
  };

  for (int ktp = 0; ktp < NT; ktp += 2) {
    bool sAll = (ktp < NT - 2);
    // ===== even body (d=0) =====
    phase(0, 0, 0);
    { gll16(stA + 32, ldsw + 24576); gll16(stA + 32 + rsA, ldsw + 28672); }
    mfma16(0);
    asm volatile("s_barrier" ::: "memory");
    phase(0, 0, 1);
    if (sAll) { gll16(stB + 64, ldsw + 32768); gll16(stB + 64 + rsB, ldsw + 36864); }
    mfma16(1);
    asm volatile("s_barrier" ::: "memory");
    phase(8192, 8192, 0);
    if (sAll) { gll16(stA + 64, ldsw + 0); gll16(stA + 64 + rsA, ldsw + 4096); }
    mfma16(0);
    asm volatile("s_barrier" ::: "memory");
    phase(8192, 8192, 1);
    if (sAll) { gll16(stB + 96, ldsw + 40960); gll16(stB + 96 + rsB, ldsw + 45056); }
    mfma16(1);
    if (sAll) asm volatile("s_waitcnt vmcnt(6)" ::: "memory");
    else asm volatile("s_waitcnt vmcnt(0)" ::: "memory");
    asm volatile("s_barrier" ::: "memory");
    // ===== odd body (d=1) =====
    phase(16384, 16384, 0);
    if (sAll) { gll16(stA + 96, ldsw + 8192); gll16(stA + 96 + rsA, ldsw + 12288); }
    mfma16(0);
    asm volatile("s_barrier" ::: "memory");
    phase(16384, 16384, 1);
    if (sAll) { gll16(stB + 128, ldsw + 49152); gll16(stB + 128 + rsB, ldsw + 53248); }
    mfma16(1);
    asm volatile("s_barrier" ::: "memory");
    phase(24576, 24576, 0);
    if (sAll) { gll16(stA + 128, ldsw + 16384); gll16(stA + 128 + rsA, ldsw + 20480); }
    mfma16(0);
    asm volatile("s_barrier" ::: "memory");
    phase(24576, 24576, 1);
    if (sAll) { gll16(stB + 160, ldsw + 57344); gll16(stB + 160 + rsB, ldsw + 61440); }
    mfma16(1);
    if (sAll) asm volatile("s_waitcnt vmcnt(6)" ::: "memory");
    asm volatile("s_barrier" ::: "memory");
    stA += 128; stB += 128;
  }

#pragma unroll
  for (int mf = 0; mf < 8; ++mf) {
#pragma unroll
    for (int rr = 0; rr < 4; ++rr) {
      int row = m0 + wm * 128 + mf * 16 + (lane >> 4) * 4 + rr;
#pragma unroll
      for (int nf = 0; nf < 4; ++nf) {
        int col = n0 + wn * 64 + nf * 16 + (lane & 15);
        float v = acc[mf][nf][rr];
        if (EPI == 0) {
          Cb[(size_t)row * N + col] = f2b(v);
        } else if (EPI == 1) {
          int b = row >> 10;
          Cf[(size_t)row * Hh + col] = hid[((size_t)b * Ss + idx[row]) * Hh + col] + v;
        } else {
          int b = row >> 10;
          Cf[((size_t)b * Ss + idx[row]) * Hh + col] = hs2[(size_t)row * Hh + col] + v * scalev[b];
        }
      }
    }
  }
}

// ---------------- 128x256 bf16 GEMM, 4-slot pipeline, pair-unrolled ----------------
// EPI 3: QKV epilogue — Q,K cols -> Cb[row][col]; V cols (>=4096) -> vTout[b][h][d][k]
template <int EPI>
__global__ __launch_bounds__(512, 2) void gemm128(
    const u16* __restrict__ A, const u16* __restrict__ Bt,
    int N, int Kd, int lda, int gm, int gw,
    u16* __restrict__ Cb,
    const float* __restrict__ hid, const int* __restrict__ idx,
    const float* __restrict__ hs2, const float* __restrict__ scalev,
    float* __restrict__ Cf, u16* __restrict__ vTout) {
  __shared__ u16 lds[49152];
  int bid = blockIdx.x;
  int xcd = bid & 7;
  int i2 = bid >> 3;
  int bm = i2 / gw;
  int bn = xcd * gw + i2 % gw;
  int m0 = bm * 128, n0 = bn * 256;
  int tid = threadIdx.x, lane = tid & 63, wv = tid >> 6;
  int wm = wv >> 2, wn = wv & 3;
  int NT = Kd >> 6;

  int P16 = wv * 64 + lane;
  int blk = P16 >> 3, up = P16 & 7;
  int uu = up ^ (blk & 7);
  int r0 = blk * 2 + (uu >> 2), cg0 = uu & 3;
  const u16* srcA = A + (size_t)(m0 + r0) * lda + cg0 * 8;
  const u16* srcB = Bt + (size_t)(n0 + r0) * Kd + cg0 * 8;
  size_t rsB = (size_t)128 * Kd;

  int offB = swz16(wn * 64 + (lane & 15), lane >> 4) * 8;
  int offA = 32768 + swz16(wm * 64 + (lane & 15), lane >> 4) * 8;
  u16* ldsw = &lds[wv * 512];

  f32x4 acc[4][4] = {};
  B8 aR[4], bR[4];

  gll16(srcB,      ldsw +     0); gll16(srcB + rsB,      ldsw +  4096); gll16(srcA,      ldsw + 32768);
  gll16(srcB + 32, ldsw +  8192); gll16(srcB + 32 + rsB, ldsw + 12288); gll16(srcA + 32, ldsw + 36864);
  gll16(srcB + 64, ldsw + 16384); gll16(srcB + 64 + rsB, ldsw + 20480); gll16(srcA + 64, ldsw + 40960);
  asm volatile("s_waitcnt vmcnt(6)" ::: "memory");
  asm volatile("s_barrier" ::: "memory");

  const u16* stA = srcA + 64;
  const u16* stB = srcB + 64;

  auto rd = [&](int s) {
#pragma unroll
    for (int f = 0; f < 4; ++f) bR[f].u = *(const uint4*)&lds[offB + s * 8192 + f * 512];
#pragma unroll
    for (int f = 0; f < 4; ++f) aR[f].u = *(const uint4*)&lds[offA + s * 4096 + f * 512];
  };
  auto mfma16 = [&]() {
    asm volatile("s_barrier" ::: "memory");
    asm volatile("s_waitcnt lgkmcnt(0)" ::: "memory");
    __builtin_amdgcn_s_setprio(1);
#pragma unroll
    for (int nf = 0; nf < 4; ++nf)
#pragma unroll
      for (int mf = 0; mf < 4; ++mf)
        acc[mf][nf] = __builtin_amdgcn_mfma_f32_16x16x32_bf16(aR[mf].v, bR[nf].v, acc[mf][nf], 0, 0, 0);
    __builtin_amdgcn_s_setprio(0);
  };

  for (int ktp = 0; ktp < NT; ktp += 2) {
    bool sAll = (ktp < NT - 2);
    rd(0);
    { gll16(stB + 32, ldsw + 24576); gll16(stB + 32 + rsB, ldsw + 28672); gll16(stA + 32, ldsw + 45056); }
    mfma16();
    asm volatile("s_waitcnt vmcnt(6)" ::: "memory");
    asm volatile("s_barrier" ::: "memory");
    rd(1);
    if (sAll) { gll16(stB + 64, ldsw + 0); gll16(stB + 64 + rsB, ldsw + 4096); gll16(stA + 64, ldsw + 32768); }
    mfma16();
    if (sAll) asm volatile("s_waitcnt vmcnt(6)" ::: "memory");
    else asm volatile("s_waitcnt vmcnt(3)" ::: "memory");
    asm volatile("s_barrier" ::: "memory");
    rd(2);
    if (sAll) { gll16(stB + 96, ldsw + 8192); gll16(stB + 96 + rsB, ldsw + 12288); gll16(stA + 96, ldsw + 36864); }
    mfma16();
    if (sAll) asm volatile("s_waitcnt vmcnt(6)" ::: "memory");
    else asm volatile("s_waitcnt vmcnt(0)" ::: "memory");
    asm volatile("s_barrier" ::: "memory");
    rd(3);
    if (sAll) { gll16(stB + 128, ldsw + 16384); gll16(stB + 128 + rsB, ldsw + 20480); gll16(stA + 128, ldsw + 40960); }
    mfma16();
    if (sAll) asm volatile("s_waitcnt vmcnt(6)" ::: "memory");
    asm volatile("s_barrier" ::: "memory");
    stA += 128; stB += 128;
  }

  if (EPI == 3) {
#pragma unroll
    for (int mf = 0; mf < 4; ++mf) {
      int rowb = m0 + wm * 64 + mf * 16 + (lane >> 4) * 4;
      int bb = rowb >> 10, kk2 = rowb & 1023;
#pragma unroll
      for (int nf = 0; nf < 4; ++nf) {
        int col = n0 + wn * 64 + nf * 16 + (lane & 15);
        if (col >= 4096) {
          int hh = (col - 4096) >> 7, dd = (col - 4096) & 127;
          ushort4 pk;
          pk.x = f2b(acc[mf][nf][0]); pk.y = f2b(acc[mf][nf][1]);
          pk.z = f2b(acc[mf][nf][2]); pk.w = f2b(acc[mf][nf][3]);
          *(ushort4*)&vTout[(((size_t)bb * 16 + hh) * 128 + dd) * 1024 + kk2] = pk;
        } else {
#pragma unroll
          for (int rr = 0; rr < 4; ++rr)
            Cb[(size_t)(rowb + rr) * N + col] = f2b(acc[mf][nf][rr]);
        }
      }
    }
    return;
  }

#pragma unroll
  for (int mf = 0; mf < 4; ++mf) {
#pragma unroll
    for (int rr = 0; rr < 4; ++rr) {
      int row = m0 + wm * 64 + mf * 16 + (lane >> 4) * 4 + rr;
#pragma unroll
      for (int nf = 0; nf < 4; ++nf) {
        int col = n0 + wn * 64 + nf * 16 + (lane & 15);
        float v = acc[mf][nf][rr];
        if (EPI == 0) {
          Cb[(size_t)row * N + col] = f2b(v);
        } else if (EPI == 1) {
          int b = row >> 10;
          Cf[(size_t)row * Hh + col] = hid[((size_t)b * Ss + idx[row]) * Hh + col] + v;
        } else {
          int b = row >> 10;
          Cf[((size_t)b * Ss + idx[row]) * Hh + col] = hs2[(size_t)row * Hh + col] + v * scalev[b];
        }
      }
    }
  }
}

// ---------------- RoPE on fused QKV buffer (stride 6144; Q,K only) ----------------
__global__ __launch_bounds__(256) void rope_qk(u16* __restrict__ qkv,
                                               const int* __restrict__ posg) {
  int gid = blockIdx.x * 256 + threadIdx.x;
  int i = gid & 63;
  int h = (gid >> 6) & 15;
  int t = gid >> 10;
  float p = (float)posg[t];
  float inv = exp2f(-(float)i * (13.287712379549449f / 64.0f));
  float ang = p * inv;
  float sv, cv;
  sincosf(ang, &sv, &cv);
  size_t base = (size_t)t * 6144 + h * DHh + i;
  u16* Q = qkv;
  u16* Kq = qkv + 2048;
  float q1 = b2f(Q[base]), q2 = b2f(Q[base + 64]);
  Q[base] = f2b(q1 * cv - q2 * sv);
  Q[base + 64] = f2b(q2 * cv + q1 * sv);
  float k1 = b2f(Kq[base]), k2 = b2f(Kq[base + 64]);
  Kq[base] = f2b(k1 * cv - k2 * sv);
  Kq[base + 64] = f2b(k2 * cv + k1 * sv);
}

// ---------------- flash attention: gll16-staged K and V^T, both-sides swizzle ----------------
// LDS: KsA [64 key][16 units] 16KB + VtA [128 d][8 units] 16KB = 32KB -> 4 blocks/CU.
// Unit swizzle: LDS unit u holds global unit u ^ (row & 7) (involution; 2-way conflicts only).
__global__ __launch_bounds__(256) void attn_k(const u16* __restrict__ QKV,
                                              const u16* __restrict__ vT,
                                              u16* __restrict__ O) {
  int qb = blockIdx.x;
  int head = blockIdx.y;
  int b = head >> 4, h = head & 15;
  int tid = threadIdx.x, lane = tid & 63, wv = tid >> 6;
  int l15 = lane & 15, lq = lane >> 4, l7 = lane & 7;
  __shared__ __align__(16) u16 KsA[8192];
  __shared__ __align__(16) u16 VtA[8192];
  u16* PsB = &KsA[wv * 1152];  // per-wave P bounce (2304 B), aliases KsA (dead after QK reads)

  // staging constants
  int key0 = tid >> 4;
  int uK = (tid & 15) ^ (key0 & 7);
  int koff = key0 * 6144 + uK * 8;            // + it*16*6144
  int d0s = tid >> 3;
  int uV = (tid & 7) ^ (d0s & 7);
  size_t voffB = ((size_t)head * 128 + d0s) * 1024 + uV * 8;  // + it*32*1024 + ks
  char* dK = (char*)KsA + wv * 1024;          // + it*4096 (+lane*16 implicit)
  char* dV = (char*)VtA + wv * 1024;

  int q0 = qb * 64 + wv * 16;
  int tokQ = b * KS + q0;
  B8 qf[4];
  const u16* qp = QKV + (size_t)(tokQ + l15) * 6144 + h * DHh;
#pragma unroll
  for (int c = 0; c < 4; ++c) qf[c].u = *(const uint4*)(qp + c * 32 + lq * 8);
  float m_run = -1e30f, l_run = 0.0f;
  f32x4 oacc[8] = {};
  int qi = q0 + l15;

  for (int ks = 0; ks <= qb * 64; ks += 64) {
    bool maskTile = (ks == qb * 64);
    __syncthreads();
    const u16* kp = QKV + (size_t)(b * KS + ks) * 6144 + 2048 + h * DHh;
    const u16* vp = vT + voffB + ks;
    gll16(kp + koff,          dK);
    gll16(kp + koff +  98304, dK + 4096);
    gll16(kp + koff + 196608, dK + 8192);
    gll16(kp + koff + 294912, dK + 12288);
    gll16(vp,          dV);
    gll16(vp + 32768,  dV + 4096);
    gll16(vp + 65536,  dV + 8192);
    gll16(vp + 98304,  dV + 12288);
    asm volatile("s_waitcnt vmcnt(0)" ::: "memory");
    __syncthreads();
    // QK^T: st[kt] = S^T tile (rows=key, cols=q)
    f32x4 st[4] = {};
#pragma unroll
    for (int c = 0; c < 4; ++c) {
#pragma unroll
      for (int kt = 0; kt < 4; ++kt) {
        B8 kf;
        kf.u = *(const uint4*)&KsA[(kt * 16 + l15) * 128 + (((c * 4 + lq) ^ l7) * 8)];
        st[kt] = __builtin_amdgcn_mfma_f32_16x16x32_bf16(kf.v, qf[c].v, st[kt], 0, 0, 0);
      }
    }
    __syncthreads();  // KsA reads complete; PsB (alias) writable
    float pmax = -INFINITY;
    if (maskTile) {
#pragma unroll
      for (int kt = 0; kt < 4; ++kt)
#pragma unroll
        for (int r = 0; r < 4; ++r) {
          int ki = ks + kt * 16 + lq * 4 + r;
          float v = st[kt][r] * 0.088388347648318447f;
          v = (ki <= qi) ? v : -INFINITY;
          st[kt][r] = v;
          pmax = fmaxf(pmax, v);
        }
    } else {
#pragma unroll
      for (int kt = 0; kt < 4; ++kt)
#pragma unroll
        for (int r = 0; r < 4; ++r) {
          float v = st[kt][r] * 0.088388347648318447f;
          st[kt][r] = v;
          pmax = fmaxf(pmax, v);
        }
    }
    pmax = fmaxf(pmax, __shfl_xor(pmax, 16));
    pmax = fmaxf(pmax, __shfl_xor(pmax, 32));
    float m_new = fmaxf(m_run, pmax);
    float alpha = __expf(m_run - m_new);
    float psum = 0.0f;
#pragma unroll
    for (int kt = 0; kt < 4; ++kt)
#pragma unroll
      for (int r = 0; r < 4; ++r) {
        float pv = __expf(st[kt][r] - m_new);
        st[kt][r] = pv;
        psum += pv;
      }
    psum += __shfl_xor(psum, 16);
    psum += __shfl_xor(psum, 32);
    l_run = l_run * alpha + psum;
    m_run = m_new;
#pragma unroll
    for (int kt = 0; kt < 4; ++kt) {
      ushort4 pk;
      pk.x = f2b(st[kt][0]); pk.y = f2b(st[kt][1]);
      pk.z = f2b(st[kt][2]); pk.w = f2b(st[kt][3]);
      *(ushort4*)&PsB[l15 * 72 + kt * 16 + lq * 4] = pk;
    }
    B8 pf0, pf1;
    pf0.u = *(const uint4*)&PsB[l15 * 72 + lq * 8];
    pf1.u = *(const uint4*)&PsB[l15 * 72 + 32 + lq * 8];
    float al0 = __shfl(alpha, lq * 4 + 0);
    float al1 = __shfl(alpha, lq * 4 + 1);
    float al2 = __shfl(alpha, lq * 4 + 2);
    float al3 = __shfl(alpha, lq * 4 + 3);
#pragma unroll
    for (int dt = 0; dt < 8; ++dt) {
      oacc[dt][0] *= al0; oacc[dt][1] *= al1;
      oacc[dt][2] *= al2; oacc[dt][3] *= al3;
    }
#pragma unroll
    for (int dt = 0; dt < 8; ++dt) {
      int d = dt * 16 + l15;
      B8 vf;
      vf.u = *(const uint4*)&VtA[d * 64 + ((lq ^ l7) * 8)];
      oacc[dt] = __builtin_amdgcn_mfma_f32_16x16x32_bf16(pf0.v, vf.v, oacc[dt], 0, 0, 0);
      vf.u = *(const uint4*)&VtA[d * 64 + (((4 + lq) ^ l7) * 8)];
      oacc[dt] = __builtin_amdgcn_mfma_f32_16x16x32_bf16(pf1.v, vf.v, oacc[dt], 0, 0, 0);
    }
  }
  float linv = 1.0f / l_run;
  float li[4];
#pragma unroll
  for (int r = 0; r < 4; ++r) li[r] = __shfl(linv, lq * 4 + r);
#pragma unroll
  for (int r = 0; r < 4; ++r) {
    int tok = tokQ + lq * 4 + r;
    u16* op = O + (size_t)tok * Hh + h * DHh;
#pragma unroll
    for (int dt = 0; dt < 8; ++dt) op[dt * 16 + l15] = f2b(oacc[dt][r] * li[r]);
  }
}

// ---------------- silu(g)*u on fused gate|up buffer (stride 16384) ----------------
__global__ __launch_bounds__(256) void silu_gu(u16* __restrict__ gu) {
  size_t gid = (size_t)blockIdx.x * 256 + threadIdx.x;
  size_t t = gid >> 10;
  int c = (int)(gid & 1023) * 8;
  u16* gp = gu + t * 16384 + c;
  const u16* upp = gp + 8192;
  B8 gv, uv;
  gv.u = *(const uint4*)gp;
  uv.u = *(const uint4*)upp;
#pragma unroll
  for (int j = 0; j < 8; ++j) {
    float x = b2f(gv.s[j]), y = b2f(uv.s[j]);
    gv.s[j] = f2b(x / (1.0f + __expf(-x)) * y);
  }
  *(uint4*)gp = gv.u;
}

extern "C" void kernel_launch(void* const* d_in, const int* in_sizes, int n_in,
                              void* d_out, int out_size, void* d_ws, size_t ws_size,
                              hipStream_t stream) {
  (void)in_sizes; (void)n_in; (void)out_size; (void)ws_size;
  const float* hid = (const float*)d_in[0];
  const int* posids = (const int*)d_in[1];
  const void* mask = d_in[2];
  const float* scores = (const float*)d_in[3];
  const float* Wq = (const float*)d_in[5];
  const float* Wk = (const float*)d_in[6];
  const float* Wv = (const float*)d_in[7];
  const float* Wo = (const float*)d_in[8];
  const float* Wg = (const float*)d_in[9];
  const float* Wu = (const float*)d_in[10];
  const float* Wd = (const float*)d_in[11];
  const float* ln1 = (const float*)d_in[12];
  const float* ln2 = (const float*)d_in[13];
  float* out = (float*)d_out;
  char* ws = (char*)d_ws;

  u16* WqkvT = (u16*)(ws + 0);            // [6144][2048] bf16
  u16* WoT   = (u16*)(ws + 25165824);     // [2048][2048]
  u16* WguT  = (u16*)(ws + 33554432);     // [16384][2048]
  u16* WdT   = (u16*)(ws + 100663296);    // [2048][8192]
  int* idx   = (int*)(ws + 134217728);
  int* posg  = (int*)(ws + 134217728 + 16384);
  float* scalev = (float*)(ws + 134217728 + 32768);
  char* R = ws + 134283264;               // 128MiB pool
  u16* hsn    = (u16*)(R);                // [4096][2048]
  u16* qkv    = (u16*)(R + 16777216);     // [4096][6144] (V third unused)
  u16* attn_o = (u16*)(R + 67108864);     // [4096][2048]
  u16* vT     = (u16*)(R + 88080384);     // [64][128][1024] = 16.7MB
  u16* gu     = (u16*)(R);                // [4096][16384] overlays (dead by then)
  float* hs2  = (float*)(ws + 268500992); // [4096][2048] f32
  u16* mnorm  = (u16*)(ws + 302055424);   // [4096][2048]

  hipMemcpyAsync(out, hid, (size_t)Bb * Ss * Hh * 4, hipMemcpyDeviceToDevice, stream);

  topk_prep<<<Bb, 256, 0, stream>>>(mask, posids, scores, idx, posg, scalev);

  transpose_w<<<dim3(64, 64), dim3(32, 8), 0, stream>>>(Wq, WqkvT, 2048, 2048);
  transpose_w<<<dim3(64, 64), dim3(32, 8), 0, stream>>>(Wk, WqkvT + 2048 * 2048, 2048, 2048);
  transpose_w<<<dim3(64, 64), dim3(32, 8), 0, stream>>>(Wv, WqkvT + 4096 * 2048, 2048, 2048);
  transpose_w<<<dim3(64, 64), dim3(32, 8), 0, stream>>>(Wo, WoT, 2048, 2048);
  transpose_w<<<dim3(256, 64), dim3(32, 8), 0, stream>>>(Wg, WguT, 2048, 8192);
  transpose_w<<<dim3(256, 64), dim3(32, 8), 0, stream>>>(Wu, WguT + 8192 * 2048, 2048, 8192);
  transpose_w<<<dim3(64, 256), dim3(32, 8), 0, stream>>>(Wd, WdT, 8192, 2048);

  rmsnorm_k<1><<<NTOK, 256, 0, stream>>>(hid, idx, ln1, hsn);

  // QKV fused: gemm128 EPI=3 (Q,K -> qkv; V -> vT transposed)
  gemm128<3><<<768, 512, 0, stream>>>(hsn, WqkvT, 6144, 2048, 2048, 32, 3, qkv,
                                      nullptr, nullptr, nullptr, nullptr, nullptr, vT);

  rope_qk<<<16384, 256, 0, stream>>>(qkv, posg);

  attn_k<<<dim3(16, 64), 256, 0, stream>>>(qkv, vT, attn_o);

  // Wo: gemm128 (gm=32, gw=1) 256 blocks
  gemm128<1><<<256, 512, 0, stream>>>(attn_o, WoT, 2048, 2048, 2048, 32, 1, nullptr,
                                      hid, idx, nullptr, nullptr, hs2, nullptr);

  rmsnorm_k<0><<<NTOK, 256, 0, stream>>>(hs2, nullptr, ln2, mnorm);

  // gate|up fused: gemm256 (gm=16, gw=8) 1024 blocks
  gemm256<0><<<1024, 512, 0, stream>>>(mnorm, WguT, 16384, 2048, 2048, 16, 8, gu,
                                       nullptr, nullptr, nullptr, nullptr, nullptr);

  silu_gu<<<16384, 256, 0, stream>>>(gu);

  // down: gemm128 (gm=32, gw=1) 256 blocks
  gemm128<2><<<256, 512, 0, stream>>>(gu, WdT, 2048, 8192, 16384, 32, 1, nullptr,
                                      nullptr, idx, hs2, scalev, out, nullptr);
}

// Round 10
// 1075.571 us; speedup vs baseline: 1.1776x; 1.0956x over previous
//
#include <hip/hip_runtime.h>
#include <hip/hip_bf16.h>
#include <stdint.h>

#define Bb 4
#define Ss 8192
#define Hh 2048
#define NHh 16
#define DHh 128
#define DFFf 8192
#define KS 1024
#define NTOK 4096

typedef unsigned short u16;
typedef __bf16 bf16x8 __attribute__((ext_vector_type(8)));
typedef float f32x4 __attribute__((ext_vector_type(4)));

union B8 { uint4 u; bf16x8 v; u16 s[8]; };

__device__ __forceinline__ float b2f(u16 x) { return __uint_as_float(((unsigned)x) << 16); }
__device__ __forceinline__ u16 f2b(float x) {
  __hip_bfloat16 h = __float2bfloat16(x);
  return *reinterpret_cast<u16*>(&h);
}

__device__ __forceinline__ void gll16(const void* g, void* l) {
  __builtin_amdgcn_global_load_lds((const __attribute__((address_space(1))) void*)g,
                                   (__attribute__((address_space(3))) void*)l, 16, 0, 0);
}

// swizzled 16B-unit index within a Rx32 bf16 region (row-pair XOR swizzle)
__device__ __forceinline__ int swz16(int r, int cg) {
  int u = ((r & 1) << 2) | cg;
  return ((r >> 1) << 3) | (u ^ ((r >> 1) & 7));
}

// ---------------- top-k index scan ----------------
__global__ void topk_prep(const void* maskp, const int* __restrict__ posids,
                          const float* __restrict__ scores,
                          int* __restrict__ idx, int* __restrict__ posg,
                          float* __restrict__ scalev) {
  int b = blockIdx.x;
  int tid = threadIdx.x, lane = tid & 63, wv = tid >> 6;
  __shared__ int wsum[4];
  __shared__ int base;
  __shared__ int mode;
  __shared__ int detCnt;
  if (tid == 0) { base = 0; detCnt = 0; }
  __syncthreads();
  {
    const unsigned char* mb = (const unsigned char*)maskp;
    int c = 0;
    for (int s = tid; s < 8192; s += 256) c += (mb[s] != 0);
    atomicAdd(&detCnt, c);
  }
  __syncthreads();
  if (tid == 0) mode = (detCnt == KS) ? 1 : 0;
  __syncthreads();
  const unsigned char* mb = (const unsigned char*)maskp;
  const int* mi = (const int*)maskp;
  for (int s0 = 0; s0 < Ss; s0 += 256) {
    int s = s0 + tid;
    int pred = mode ? (mb[(size_t)b * Ss + s] != 0) : (mi[(size_t)b * Ss + s] != 0);
    unsigned long long bal = __ballot(pred);
    int lp = __popcll(bal & ((1ull << lane) - 1ull));
    int wtot = __popcll(bal);
    if (lane == 0) wsum[wv] = wtot;
    __syncthreads();
    int woff = 0;
    for (int w = 0; w < wv; ++w) woff += wsum[w];
    int tot = wsum[0] + wsum[1] + wsum[2] + wsum[3];
    int p = base + woff + lp;
    if (pred && p < KS) {
      idx[b * KS + p] = s;
      posg[b * KS + p] = posids[(size_t)b * Ss + s];
    }
    __syncthreads();
    if (tid == 0) base += tot;
    __syncthreads();
  }
  if (b == 0 && tid < Bb) scalev[tid] = 0.5f * 1.0f + (scores[tid] - 0.5f) * 1.0f;
}

// ---------------- weight transpose fp32 -> bf16 ----------------
// MODE 0: out row = c. MODE 1 (gate): row = (c>>5)*64 + (c&31). MODE 2 (up): +32.
template <int MODE>
__global__ void transpose_w(const float* __restrict__ in, u16* __restrict__ out, int R, int C) {
  __shared__ float tile[32][33];
  int tx = threadIdx.x, ty = threadIdx.y;
  int c0 = blockIdx.x * 32, r0 = blockIdx.y * 32;
  for (int j = ty; j < 32; j += 8) tile[j][tx] = in[(size_t)(r0 + j) * C + c0 + tx];
  __syncthreads();
  for (int j = ty; j < 32; j += 8) {
    int c = c0 + j;
    size_t row = (MODE == 0) ? c : (size_t)((c >> 5) << 6) + (c & 31) + (MODE == 2 ? 32 : 0);
    out[row * R + r0 + tx] = f2b(tile[tx][j]);
  }
}

// ---------------- RMSNorm ----------------
template <int GATHER>
__global__ __launch_bounds__(256) void rmsnorm_k(const float* __restrict__ src0,
                                                 const int* __restrict__ idx,
                                                 const float* __restrict__ w,
                                                 u16* __restrict__ out) {
  int t = blockIdx.x;
  const float* src;
  if (GATHER) { int b = t >> 10; src = src0 + ((size_t)b * Ss + idx[t]) * Hh; }
  else src = src0 + (size_t)t * Hh;
  int tid = threadIdx.x, lane = tid & 63, wv = tid >> 6;
  float4 x0 = *(const float4*)(src + tid * 8);
  float4 x1 = *(const float4*)(src + tid * 8 + 4);
  float ss = x0.x * x0.x + x0.y * x0.y + x0.z * x0.z + x0.w * x0.w +
             x1.x * x1.x + x1.y * x1.y + x1.z * x1.z + x1.w * x1.w;
  for (int o = 32; o; o >>= 1) ss += __shfl_down(ss, o);
  __shared__ float wred[4];
  if (lane == 0) wred[wv] = ss;
  __syncthreads();
  float tot = wred[0] + wred[1] + wred[2] + wred[3];
  float r = rsqrtf(tot * (1.0f / Hh) + 1e-5f);
  const float* wp = w + tid * 8;
  u16* op = out + (size_t)t * Hh + tid * 8;
  float xs[8] = {x0.x, x0.y, x0.z, x0.w, x1.x, x1.y, x1.z, x1.w};
#pragma unroll
  for (int j = 0; j < 8; ++j) op[j] = f2b(xs[j] * r * wp[j]);
}

// ---------------- 256x256 8-phase bf16 GEMM, pair-unrolled, const offsets ----------------
// EPI 4: interleaved gate/up -> writes silu(g)*u to Cb [4096][8192]
template <int EPI>
__global__ __launch_bounds__(512, 2) void gemm256(
    const u16* __restrict__ A, const u16* __restrict__ Bt,
    int N, int Kd, int lda, int gm, int gw,
    u16* __restrict__ Cb,
    const float* __restrict__ hid, const int* __restrict__ idx,
    const float* __restrict__ hs2, const float* __restrict__ scalev,
    float* __restrict__ Cf) {
  __shared__ u16 lds[65536];
  int bid = blockIdx.x;
  int xcd = bid & 7;
  int i2 = bid >> 3;
  int bm = i2 / gw;             // bn-fast within XCD strip
  int bn = xcd * gw + i2 % gw;
  int m0 = bm * 256, n0 = bn * 256;
  int tid = threadIdx.x, lane = tid & 63, wv = tid >> 6;
  int wm = wv >> 2, wn = wv & 3;
  int NT = Kd >> 6;

  int P16 = wv * 64 + lane;
  int blk = P16 >> 3, up = P16 & 7;
  int uu = up ^ (blk & 7);
  int r0 = blk * 2 + (uu >> 2), cg0 = uu & 3;
  const u16* srcA = A + (size_t)(m0 + r0) * lda + cg0 * 8;
  const u16* srcB = Bt + (size_t)(n0 + r0) * Kd + cg0 * 8;
  size_t rsA = (size_t)128 * lda, rsB = (size_t)128 * Kd;

  int offA = swz16(wm * 128 + (lane & 15), lane >> 4) * 8;
  int offB = 32768 + swz16(wn * 64 + (lane & 15), lane >> 4) * 8;
  u16* ldsw = &lds[wv * 512];

  f32x4 acc[8][4] = {};
  B8 aR[4], bR[4];

  gll16(srcB,      ldsw + 32768); gll16(srcB + rsB,      ldsw + 36864);
  gll16(srcA,      ldsw +     0); gll16(srcA + rsA,      ldsw +  4096);
  gll16(srcB + 32, ldsw + 40960); gll16(srcB + 32 + rsB, ldsw + 45056);
  gll16(srcA + 32, ldsw +  8192); gll16(srcA + 32 + rsA, ldsw + 12288);
  gll16(srcB + 64, ldsw + 49152); gll16(srcB + 64 + rsB, ldsw + 53248);
  gll16(srcA + 64, ldsw + 16384); gll16(srcA + 64 + rsA, ldsw + 20480);
  gll16(srcB + 96, ldsw + 57344); gll16(srcB + 96 + rsB, ldsw + 61440);
  asm volatile("s_waitcnt vmcnt(6)" ::: "memory");
  asm volatile("s_barrier" ::: "memory");

  const u16* stA = srcA + 64;
  const u16* stB = srcB + 64;

  auto phase = [&](int abase, int bbase, int mh) {
    if (mh == 0) {
#pragma unroll
      for (int nf = 0; nf < 4; ++nf) bR[nf].u = *(const uint4*)&lds[offB + bbase + nf * 512];
    }
#pragma unroll
    for (int i3 = 0; i3 < 4; ++i3)
      aR[i3].u = *(const uint4*)&lds[offA + abase + (i3 + 4 * mh) * 512];
  };
  auto mfma16 = [&](int mh) {
    asm volatile("s_barrier" ::: "memory");
    asm volatile("s_waitcnt lgkmcnt(0)" ::: "memory");
    __builtin_amdgcn_s_setprio(1);
#pragma unroll
    for (int nf = 0; nf < 4; ++nf)
#pragma unroll
      for (int i3 = 0; i3 < 4; ++i3)
        acc[mh * 4 + i3][nf] =
            __builtin_amdgcn_mfma_f32_16x16x32_bf16(aR[i3].v, bR[nf].v, acc[mh * 4 + i3][nf], 0, 0, 0);
    __builtin_amdgcn_s_setprio(0);
  };

  for (int ktp = 0; ktp < NT; ktp += 2) {
    bool sAll = (ktp < NT - 2);
    phase(0, 0, 0);
    { gll16(stA + 32, ldsw + 24576); gll16(stA + 32 + rsA, ldsw + 28672); }
    mfma16(0);
    asm volatile("s_barrier" ::: "memory");
    phase(0, 0, 1);
    if (sAll) { gll16(stB + 64, ldsw + 32768); gll16(stB + 64 + rsB, ldsw + 36864); }
    mfma16(1);
    asm volatile("s_barrier" ::: "memory");
    phase(8192, 8192, 0);
    if (sAll) { gll16(stA + 64, ldsw + 0); gll16(stA + 64 + rsA, ldsw + 4096); }
    mfma16(0);
    asm volatile("s_barrier" ::: "memory");
    phase(8192, 8192, 1);
    if (sAll) { gll16(stB + 96, ldsw + 40960); gll16(stB + 96 + rsB, ldsw + 45056); }
    mfma16(1);
    if (sAll) asm volatile("s_waitcnt vmcnt(6)" ::: "memory");
    else asm volatile("s_waitcnt vmcnt(0)" ::: "memory");
    asm volatile("s_barrier" ::: "memory");
    phase(16384, 16384, 0);
    if (sAll) { gll16(stA + 96, ldsw + 8192); gll16(stA + 96 + rsA, ldsw + 12288); }
    mfma16(0);
    asm volatile("s_barrier" ::: "memory");
    phase(16384, 16384, 1);
    if (sAll) { gll16(stB + 128, ldsw + 49152); gll16(stB + 128 + rsB, ldsw + 53248); }
    mfma16(1);
    asm volatile("s_barrier" ::: "memory");
    phase(24576, 24576, 0);
    if (sAll) { gll16(stA + 128, ldsw + 16384); gll16(stA + 128 + rsA, ldsw + 20480); }
    mfma16(0);
    asm volatile("s_barrier" ::: "memory");
    phase(24576, 24576, 1);
    if (sAll) { gll16(stB + 160, ldsw + 57344); gll16(stB + 160 + rsB, ldsw + 61440); }
    mfma16(1);
    if (sAll) asm volatile("s_waitcnt vmcnt(6)" ::: "memory");
    asm volatile("s_barrier" ::: "memory");
    stA += 128; stB += 128;
  }

  if (EPI == 4) {
    int gcol0 = ((n0 + wn * 64) >> 1) + (lane & 15);
#pragma unroll
    for (int mf = 0; mf < 8; ++mf) {
#pragma unroll
      for (int rr = 0; rr < 4; ++rr) {
        int row = m0 + wm * 128 + mf * 16 + (lane >> 4) * 4 + rr;
#pragma unroll
        for (int nf = 0; nf < 2; ++nf) {
          float g = acc[mf][nf][rr];
          float u = acc[mf][nf + 2][rr];
          Cb[(size_t)row * 8192 + gcol0 + nf * 16] = f2b(g / (1.0f + __expf(-g)) * u);
        }
      }
    }
    return;
  }

#pragma unroll
  for (int mf = 0; mf < 8; ++mf) {
#pragma unroll
    for (int rr = 0; rr < 4; ++rr) {
      int row = m0 + wm * 128 + mf * 16 + (lane >> 4) * 4 + rr;
#pragma unroll
      for (int nf = 0; nf < 4; ++nf) {
        int col = n0 + wn * 64 + nf * 16 + (lane & 15);
        float v = acc[mf][nf][rr];
        if (EPI == 0) {
          Cb[(size_t)row * N + col] = f2b(v);
        } else if (EPI == 1) {
          int b = row >> 10;
          Cf[(size_t)row * Hh + col] = hid[((size_t)b * Ss + idx[row]) * Hh + col] + v;
        } else {
          int b = row >> 10;
          Cf[((size_t)b * Ss + idx[row]) * Hh + col] = hs2[(size_t)row * Hh + col] + v * scalev[b];
        }
      }
    }
  }
}

// ---------------- 128x256 bf16 GEMM, 4-slot pipeline, pair-unrolled ----------------
// EPI 3: QKV epilogue — Q,K cols -> Cb[row][col]; V cols (>=4096) -> vTout[b][h][d][k]
template <int EPI>
__global__ __launch_bounds__(512, 2) void gemm128(
    const u16* __restrict__ A, const u16* __restrict__ Bt,
    int N, int Kd, int lda, int gm, int gw,
    u16* __restrict__ Cb,
    const float* __restrict__ hid, const int* __restrict__ idx,
    const float* __restrict__ hs2, const float* __restrict__ scalev,
    float* __restrict__ Cf, u16* __restrict__ vTout) {
  __shared__ u16 lds[49152];
  int bid = blockIdx.x;
  int xcd = bid & 7;
  int i2 = bid >> 3;
  int bm = i2 / gw;
  int bn = xcd * gw + i2 % gw;
  int m0 = bm * 128, n0 = bn * 256;
  int tid = threadIdx.x, lane = tid & 63, wv = tid >> 6;
  int wm = wv >> 2, wn = wv & 3;
  int NT = Kd >> 6;

  int P16 = wv * 64 + lane;
  int blk = P16 >> 3, up = P16 & 7;
  int uu = up ^ (blk & 7);
  int r0 = blk * 2 + (uu >> 2), cg0 = uu & 3;
  const u16* srcA = A + (size_t)(m0 + r0) * lda + cg0 * 8;
  const u16* srcB = Bt + (size_t)(n0 + r0) * Kd + cg0 * 8;
  size_t rsB = (size_t)128 * Kd;

  int offB = swz16(wn * 64 + (lane & 15), lane >> 4) * 8;
  int offA = 32768 + swz16(wm * 64 + (lane & 15), lane >> 4) * 8;
  u16* ldsw = &lds[wv * 512];

  f32x4 acc[4][4] = {};
  B8 aR[4], bR[4];

  gll16(srcB,      ldsw +     0); gll16(srcB + rsB,      ldsw +  4096); gll16(srcA,      ldsw + 32768);
  gll16(srcB + 32, ldsw +  8192); gll16(srcB + 32 + rsB, ldsw + 12288); gll16(srcA + 32, ldsw + 36864);
  gll16(srcB + 64, ldsw + 16384); gll16(srcB + 64 + rsB, ldsw + 20480); gll16(srcA + 64, ldsw + 40960);
  asm volatile("s_waitcnt vmcnt(6)" ::: "memory");
  asm volatile("s_barrier" ::: "memory");

  const u16* stA = srcA + 64;
  const u16* stB = srcB + 64;

  auto rd = [&](int s) {
#pragma unroll
    for (int f = 0; f < 4; ++f) bR[f].u = *(const uint4*)&lds[offB + s * 8192 + f * 512];
#pragma unroll
    for (int f = 0; f < 4; ++f) aR[f].u = *(const uint4*)&lds[offA + s * 4096 + f * 512];
  };
  auto mfma16 = [&]() {
    asm volatile("s_barrier" ::: "memory");
    asm volatile("s_waitcnt lgkmcnt(0)" ::: "memory");
    __builtin_amdgcn_s_setprio(1);
#pragma unroll
    for (int nf = 0; nf < 4; ++nf)
#pragma unroll
      for (int mf = 0; mf < 4; ++mf)
        acc[mf][nf] = __builtin_amdgcn_mfma_f32_16x16x32_bf16(aR[mf].v, bR[nf].v, acc[mf][nf], 0, 0, 0);
    __builtin_amdgcn_s_setprio(0);
  };

  for (int ktp = 0; ktp < NT; ktp += 2) {
    bool sAll = (ktp < NT - 2);
    rd(0);
    { gll16(stB + 32, ldsw + 24576); gll16(stB + 32 + rsB, ldsw + 28672); gll16(stA + 32, ldsw + 45056); }
    mfma16();
    asm volatile("s_waitcnt vmcnt(6)" ::: "memory");
    asm volatile("s_barrier" ::: "memory");
    rd(1);
    if (sAll) { gll16(stB + 64, ldsw + 0); gll16(stB + 64 + rsB, ldsw + 4096); gll16(stA + 64, ldsw + 32768); }
    mfma16();
    if (sAll) asm volatile("s_waitcnt vmcnt(6)" ::: "memory");
    else asm volatile("s_waitcnt vmcnt(3)" ::: "memory");
    asm volatile("s_barrier" ::: "memory");
    rd(2);
    if (sAll) { gll16(stB + 96, ldsw + 8192); gll16(stB + 96 + rsB, ldsw + 12288); gll16(stA + 96, ldsw + 36864); }
    mfma16();
    if (sAll) asm volatile("s_waitcnt vmcnt(6)" ::: "memory");
    else asm volatile("s_waitcnt vmcnt(0)" ::: "memory");
    asm volatile("s_barrier" ::: "memory");
    rd(3);
    if (sAll) { gll16(stB + 128, ldsw + 16384); gll16(stB + 128 + rsB, ldsw + 20480); gll16(stA + 128, ldsw + 40960); }
    mfma16();
    if (sAll) asm volatile("s_waitcnt vmcnt(6)" ::: "memory");
    asm volatile("s_barrier" ::: "memory");
    stA += 128; stB += 128;
  }

  if (EPI == 3) {
#pragma unroll
    for (int mf = 0; mf < 4; ++mf) {
      int rowb = m0 + wm * 64 + mf * 16 + (lane >> 4) * 4;
      int bb = rowb >> 10, kk2 = rowb & 1023;
#pragma unroll
      for (int nf = 0; nf < 4; ++nf) {
        int col = n0 + wn * 64 + nf * 16 + (lane & 15);
        if (col >= 4096) {
          int hh = (col - 4096) >> 7, dd = (col - 4096) & 127;
          ushort4 pk;
          pk.x = f2b(acc[mf][nf][0]); pk.y = f2b(acc[mf][nf][1]);
          pk.z = f2b(acc[mf][nf][2]); pk.w = f2b(acc[mf][nf][3]);
          *(ushort4*)&vTout[(((size_t)bb * 16 + hh) * 128 + dd) * 1024 + kk2] = pk;
        } else {
#pragma unroll
          for (int rr = 0; rr < 4; ++rr)
            Cb[(size_t)(rowb + rr) * N + col] = f2b(acc[mf][nf][rr]);
        }
      }
    }
    return;
  }

#pragma unroll
  for (int mf = 0; mf < 4; ++mf) {
#pragma unroll
    for (int rr = 0; rr < 4; ++rr) {
      int row = m0 + wm * 64 + mf * 16 + (lane >> 4) * 4 + rr;
#pragma unroll
      for (int nf = 0; nf < 4; ++nf) {
        int col = n0 + wn * 64 + nf * 16 + (lane & 15);
        float v = acc[mf][nf][rr];
        if (EPI == 0) {
          Cb[(size_t)row * N + col] = f2b(v);
        } else if (EPI == 1) {
          int b = row >> 10;
          Cf[(size_t)row * Hh + col] = hid[((size_t)b * Ss + idx[row]) * Hh + col] + v;
        } else {
          int b = row >> 10;
          Cf[((size_t)b * Ss + idx[row]) * Hh + col] = hs2[(size_t)row * Hh + col] + v * scalev[b];
        }
      }
    }
  }
}

// ---------------- RoPE on fused QKV buffer (stride 6144; Q,K only) ----------------
__global__ __launch_bounds__(256) void rope_qk(u16* __restrict__ qkv,
                                               const int* __restrict__ posg) {
  int gid = blockIdx.x * 256 + threadIdx.x;
  int i = gid & 63;
  int h = (gid >> 6) & 15;
  int t = gid >> 10;
  float p = (float)posg[t];
  float inv = exp2f(-(float)i * (13.287712379549449f / 64.0f));
  float ang = p * inv;
  float sv, cv;
  __sincosf(ang, &sv, &cv);
  size_t base = (size_t)t * 6144 + h * DHh + i;
  u16* Q = qkv;
  u16* Kq = qkv + 2048;
  float q1 = b2f(Q[base]), q2 = b2f(Q[base + 64]);
  Q[base] = f2b(q1 * cv - q2 * sv);
  Q[base + 64] = f2b(q2 * cv + q1 * sv);
  float k1 = b2f(Kq[base]), k2 = b2f(Kq[base + 64]);
  Kq[base] = f2b(k1 * cv - k2 * sv);
  Kq[base + 64] = f2b(k2 * cv + k1 * sv);
}

// ---------------- flash attention: KVBLK=128, gll16-staged K and V^T, both-sides swizzle ----------------
// LDS: KsA [128 key][16 units] 32KB + VtA [128 d][16 units] 32KB = 64KB -> 2 blocks/CU.
// P-bounce aliases KsA (dead after QK reads within the tile).
__global__ __launch_bounds__(256) void attn_k(const u16* __restrict__ QKV,
                                              const u16* __restrict__ vT,
                                              u16* __restrict__ O) {
  int qb = blockIdx.x;
  int head = blockIdx.y;
  int b = head >> 4, h = head & 15;
  int tid = threadIdx.x, lane = tid & 63, wv = tid >> 6;
  int l15 = lane & 15, lq = lane >> 4, l7 = lane & 7;
  __shared__ __align__(16) u16 KsA[16384];
  __shared__ __align__(16) u16 VtA[16384];
  u16* PsB = &KsA[wv * 2176];  // per-wave P bounce [16 q][136], 4352 B, aliases KsA

  // staging constants (per-lane source, wave-uniform dest)
  int keyr = tid >> 4;                           // row within 16-row group, + i*16
  int uphys = tid & 15;
  size_t koff0 = (size_t)keyr * 6144 + ((uphys ^ (keyr & 7)) * 8);
  size_t voff0 = (size_t)keyr * 1024 + ((uphys ^ (keyr & 7)) * 8);  // d-row uses same tid>>4 pattern
  char* dK = (char*)KsA + wv * 1024;
  char* dV = (char*)VtA + wv * 1024;

  int q0 = qb * 64 + wv * 16;
  int tokQ = b * KS + q0;
  B8 qf[4];
  const u16* qp = QKV + (size_t)(tokQ + l15) * 6144 + h * DHh;
#pragma unroll
  for (int c = 0; c < 4; ++c) qf[c].u = *(const uint4*)(qp + c * 32 + lq * 8);
  float m_run = -1e30f, l_run = 0.0f;
  f32x4 oacc[8] = {};
  int qi = q0 + l15;

  int nt = (qb >> 1) + 1;  // tiles of 128 keys
  for (int t = 0; t < nt; ++t) {
    int ks = t * 128;
    bool maskTile = (t == nt - 1);
    __syncthreads();
    const u16* kp = QKV + (size_t)(b * KS + ks) * 6144 + 2048 + h * DHh + koff0;
    const u16* vp = vT + ((size_t)head * 128) * 1024 + ks + voff0;
#pragma unroll
    for (int i = 0; i < 8; ++i) {
      gll16(kp + (size_t)i * 16 * 6144, dK + i * 4096);
      gll16(vp + (size_t)i * 16 * 1024, dV + i * 4096);
    }
    asm volatile("s_waitcnt vmcnt(0)" ::: "memory");
    __syncthreads();
    // QK^T: st[kt] = S^T tile (rows=key kt*16.., cols=q)
    f32x4 st[8] = {};
#pragma unroll
    for (int c = 0; c < 4; ++c) {
#pragma unroll
      for (int kt = 0; kt < 8; ++kt) {
        B8 kf;
        kf.u = *(const uint4*)&KsA[(kt * 16 + l15) * 128 + (((c * 4 + lq) ^ l7) * 8)];
        st[kt] = __builtin_amdgcn_mfma_f32_16x16x32_bf16(kf.v, qf[c].v, st[kt], 0, 0, 0);
      }
    }
    __syncthreads();  // KsA reads complete; PsB (alias) writable
    float pmax = -INFINITY;
    if (maskTile) {
#pragma unroll
      for (int kt = 0; kt < 8; ++kt)
#pragma unroll
        for (int r = 0; r < 4; ++r) {
          int ki = ks + kt * 16 + lq * 4 + r;
          float v = st[kt][r] * 0.088388347648318447f;
          v = (ki <= qi) ? v : -INFINITY;
          st[kt][r] = v;
          pmax = fmaxf(pmax, v);
        }
    } else {
#pragma unroll
      for (int kt = 0; kt < 8; ++kt)
#pragma unroll
        for (int r = 0; r < 4; ++r) {
          float v = st[kt][r] * 0.088388347648318447f;
          st[kt][r] = v;
          pmax = fmaxf(pmax, v);
        }
    }
    pmax = fmaxf(pmax, __shfl_xor(pmax, 16));
    pmax = fmaxf(pmax, __shfl_xor(pmax, 32));
    float m_new = fmaxf(m_run, pmax);
    float alpha = __expf(m_run - m_new);
    float psum = 0.0f;
#pragma unroll
    for (int kt = 0; kt < 8; ++kt)
#pragma unroll
      for (int r = 0; r < 4; ++r) {
        float pv = __expf(st[kt][r] - m_new);
        st[kt][r] = pv;
        psum += pv;
      }
    psum += __shfl_xor(psum, 16);
    psum += __shfl_xor(psum, 32);
    l_run = l_run * alpha + psum;
    m_run = m_new;
#pragma unroll
    for (int kt = 0; kt < 8; ++kt) {
      ushort4 pk;
      pk.x = f2b(st[kt][0]); pk.y = f2b(st[kt][1]);
      pk.z = f2b(st[kt][2]); pk.w = f2b(st[kt][3]);
      *(ushort4*)&PsB[l15 * 136 + kt * 16 + lq * 4] = pk;
    }
    B8 pf[4];
#pragma unroll
    for (int kslot = 0; kslot < 4; ++kslot)
      pf[kslot].u = *(const uint4*)&PsB[l15 * 136 + kslot * 32 + lq * 8];
    float al0 = __shfl(alpha, lq * 4 + 0);
    float al1 = __shfl(alpha, lq * 4 + 1);
    float al2 = __shfl(alpha, lq * 4 + 2);
    float al3 = __shfl(alpha, lq * 4 + 3);
#pragma unroll
    for (int dt = 0; dt < 8; ++dt) {
      oacc[dt][0] *= al0; oacc[dt][1] *= al1;
      oacc[dt][2] *= al2; oacc[dt][3] *= al3;
    }
#pragma unroll
    for (int dt = 0; dt < 8; ++dt) {
      int d = dt * 16 + l15;
#pragma unroll
      for (int kslot = 0; kslot < 4; ++kslot) {
        B8 vf;
        vf.u = *(const uint4*)&VtA[d * 128 + (((kslot * 4 + lq) ^ l7) * 8)];
        oacc[dt] = __builtin_amdgcn_mfma_f32_16x16x32_bf16(pf[kslot].v, vf.v, oacc[dt], 0, 0, 0);
      }
    }
  }
  float linv = 1.0f / l_run;
  float li[4];
#pragma unroll
  for (int r = 0; r < 4; ++r) li[r] = __shfl(linv, lq * 4 + r);
#pragma unroll
  for (int r = 0; r < 4; ++r) {
    int tok = tokQ + lq * 4 + r;
    u16* op = O + (size_t)tok * Hh + h * DHh;
#pragma unroll
    for (int dt = 0; dt < 8; ++dt) op[dt * 16 + l15] = f2b(oacc[dt][r] * li[r]);
  }
}

extern "C" void kernel_launch(void* const* d_in, const int* in_sizes, int n_in,
                              void* d_out, int out_size, void* d_ws, size_t ws_size,
                              hipStream_t stream) {
  (void)in_sizes; (void)n_in; (void)out_size; (void)ws_size;
  const float* hid = (const float*)d_in[0];
  const int* posids = (const int*)d_in[1];
  const void* mask = d_in[2];
  const float* scores = (const float*)d_in[3];
  const float* Wq = (const float*)d_in[5];
  const float* Wk = (const float*)d_in[6];
  const float* Wv = (const float*)d_in[7];
  const float* Wo = (const float*)d_in[8];
  const float* Wg = (const float*)d_in[9];
  const float* Wu = (const float*)d_in[10];
  const float* Wd = (const float*)d_in[11];
  const float* ln1 = (const float*)d_in[12];
  const float* ln2 = (const float*)d_in[13];
  float* out = (float*)d_out;
  char* ws = (char*)d_ws;

  u16* WqkvT = (u16*)(ws + 0);            // [6144][2048] bf16
  u16* WoT   = (u16*)(ws + 25165824);     // [2048][2048]
  u16* WguT  = (u16*)(ws + 33554432);     // [16384][2048] interleaved g/u per 64-row block
  u16* WdT   = (u16*)(ws + 100663296);    // [2048][8192]
  int* idx   = (int*)(ws + 134217728);
  int* posg  = (int*)(ws + 134217728 + 16384);
  float* scalev = (float*)(ws + 134217728 + 32768);
  char* R = ws + 134283264;               // 128MiB pool
  u16* hsn    = (u16*)(R);                // [4096][2048]
  u16* qkv    = (u16*)(R + 16777216);     // [4096][6144] (V third unused)
  u16* attn_o = (u16*)(R + 67108864);     // [4096][2048]
  u16* vT     = (u16*)(R + 88080384);     // [64][128][1024]
  u16* gu2    = (u16*)(R);                // [4096][8192] silu(g)*u, overlays hsn/qkv (dead)
  float* hs2  = (float*)(ws + 268500992); // [4096][2048] f32
  u16* mnorm  = (u16*)(ws + 302055424);   // [4096][2048]

  hipMemcpyAsync(out, hid, (size_t)Bb * Ss * Hh * 4, hipMemcpyDeviceToDevice, stream);

  topk_prep<<<Bb, 256, 0, stream>>>(mask, posids, scores, idx, posg, scalev);

  transpose_w<0><<<dim3(64, 64), dim3(32, 8), 0, stream>>>(Wq, WqkvT, 2048, 2048);
  transpose_w<0><<<dim3(64, 64), dim3(32, 8), 0, stream>>>(Wk, WqkvT + 2048 * 2048, 2048, 2048);
  transpose_w<0><<<dim3(64, 64), dim3(32, 8), 0, stream>>>(Wv, WqkvT + 4096 * 2048, 2048, 2048);
  transpose_w<0><<<dim3(64, 64), dim3(32, 8), 0, stream>>>(Wo, WoT, 2048, 2048);
  transpose_w<1><<<dim3(256, 64), dim3(32, 8), 0, stream>>>(Wg, WguT, 2048, 8192);
  transpose_w<2><<<dim3(256, 64), dim3(32, 8), 0, stream>>>(Wu, WguT, 2048, 8192);
  transpose_w<0><<<dim3(64, 256), dim3(32, 8), 0, stream>>>(Wd, WdT, 8192, 2048);

  rmsnorm_k<1><<<NTOK, 256, 0, stream>>>(hid, idx, ln1, hsn);

  // QKV fused: gemm128 EPI=3 (Q,K -> qkv; V -> vT transposed)
  gemm128<3><<<768, 512, 0, stream>>>(hsn, WqkvT, 6144, 2048, 2048, 32, 3, qkv,
                                      nullptr, nullptr, nullptr, nullptr, nullptr, vT);

  rope_qk<<<16384, 256, 0, stream>>>(qkv, posg);

  attn_k<<<dim3(16, 64), 256, 0, stream>>>(qkv, vT, attn_o);

  // Wo: gemm128 (gm=32, gw=1) 256 blocks
  gemm128<1><<<256, 512, 0, stream>>>(attn_o, WoT, 2048, 2048, 2048, 32, 1, nullptr,
                                      hid, idx, nullptr, nullptr, hs2, nullptr);

  rmsnorm_k<0><<<NTOK, 256, 0, stream>>>(hs2, nullptr, ln2, mnorm);

  // gate|up fused + silu epilogue: gemm256 EPI=4 -> gu2 [4096][8192]
  gemm256<4><<<1024, 512, 0, stream>>>(mnorm, WguT, 16384, 2048, 2048, 16, 8, gu2,
                                       nullptr, nullptr, nullptr, nullptr, nullptr);

  // down: gemm128 (gm=32, gw=1) 256 blocks, A = gu2 (lda 8192, K 8192)
  gemm128<2><<<256, 512, 0, stream>>>(gu2, WdT, 2048, 8192, 8192, 32, 1, nullptr,
                                      nullptr, idx, hs2, scalev, out, nullptr);
}

// Round 11
// 1034.799 us; speedup vs baseline: 1.2239x; 1.0394x over previous
//
#include <hip/hip_runtime.h>
#include <hip/hip_bf16.h>
#include <stdint.h>

#define Bb 4
#define Ss 8192
#define Hh 2048
#define NHh 16
#define DHh 128
#define DFFf 8192
#define KS 1024
#define NTOK 4096

typedef unsigned short u16;
typedef __bf16 bf16x8 __attribute__((ext_vector_type(8)));
typedef float f32x4 __attribute__((ext_vector_type(4)));

union B8 { uint4 u; bf16x8 v; u16 s[8]; };

__device__ __forceinline__ float b2f(u16 x) { return __uint_as_float(((unsigned)x) << 16); }
__device__ __forceinline__ u16 f2b(float x) {
  __hip_bfloat16 h = __float2bfloat16(x);
  return *reinterpret_cast<u16*>(&h);
}

__device__ __forceinline__ void gll16(const void* g, void* l) {
  __builtin_amdgcn_global_load_lds((const __attribute__((address_space(1))) void*)g,
                                   (__attribute__((address_space(3))) void*)l, 16, 0, 0);
}

__device__ __forceinline__ int swz16(int r, int cg) {
  int u = ((r & 1) << 2) | cg;
  return ((r >> 1) << 3) | (u ^ ((r >> 1) & 7));
}

// ---------------- top-k index scan ----------------
__global__ void topk_prep(const void* maskp, const int* __restrict__ posids,
                          const float* __restrict__ scores,
                          int* __restrict__ idx, int* __restrict__ posg,
                          float* __restrict__ scalev) {
  int b = blockIdx.x;
  int tid = threadIdx.x, lane = tid & 63, wv = tid >> 6;
  __shared__ int wsum[4];
  __shared__ int base;
  __shared__ int mode;
  __shared__ int detCnt;
  if (tid == 0) { base = 0; detCnt = 0; }
  __syncthreads();
  {
    const unsigned char* mb = (const unsigned char*)maskp;
    int c = 0;
    for (int s = tid; s < 8192; s += 256) c += (mb[s] != 0);
    atomicAdd(&detCnt, c);
  }
  __syncthreads();
  if (tid == 0) mode = (detCnt == KS) ? 1 : 0;
  __syncthreads();
  const unsigned char* mb = (const unsigned char*)maskp;
  const int* mi = (const int*)maskp;
  for (int s0 = 0; s0 < Ss; s0 += 256) {
    int s = s0 + tid;
    int pred = mode ? (mb[(size_t)b * Ss + s] != 0) : (mi[(size_t)b * Ss + s] != 0);
    unsigned long long bal = __ballot(pred);
    int lp = __popcll(bal & ((1ull << lane) - 1ull));
    int wtot = __popcll(bal);
    if (lane == 0) wsum[wv] = wtot;
    __syncthreads();
    int woff = 0;
    for (int w = 0; w < wv; ++w) woff += wsum[w];
    int tot = wsum[0] + wsum[1] + wsum[2] + wsum[3];
    int p = base + woff + lp;
    if (pred && p < KS) {
      idx[b * KS + p] = s;
      posg[b * KS + p] = posids[(size_t)b * Ss + s];
    }
    __syncthreads();
    if (tid == 0) base += tot;
    __syncthreads();
  }
  if (b == 0 && tid < Bb) scalev[tid] = 0.5f * 1.0f + (scores[tid] - 0.5f) * 1.0f;
}

// ---------------- weight transpose fp32 -> bf16 ----------------
template <int MODE>
__global__ void transpose_w(const float* __restrict__ in, u16* __restrict__ out, int R, int C) {
  __shared__ float tile[32][33];
  int tx = threadIdx.x, ty = threadIdx.y;
  int c0 = blockIdx.x * 32, r0 = blockIdx.y * 32;
  for (int j = ty; j < 32; j += 8) tile[j][tx] = in[(size_t)(r0 + j) * C + c0 + tx];
  __syncthreads();
  for (int j = ty; j < 32; j += 8) {
    int c = c0 + j;
    size_t row = (MODE == 0) ? c : (size_t)((c >> 5) << 6) + (c & 31) + (MODE == 2 ? 32 : 0);
    out[row * R + r0 + tx] = f2b(tile[tx][j]);
  }
}

// ---------------- RMSNorm ----------------
template <int GATHER>
__global__ __launch_bounds__(256) void rmsnorm_k(const float* __restrict__ src0,
                                                 const int* __restrict__ idx,
                                                 const float* __restrict__ w,
                                                 u16* __restrict__ out) {
  int t = blockIdx.x;
  const float* src;
  if (GATHER) { int b = t >> 10; src = src0 + ((size_t)b * Ss + idx[t]) * Hh; }
  else src = src0 + (size_t)t * Hh;
  int tid = threadIdx.x, lane = tid & 63, wv = tid >> 6;
  float4 x0 = *(const float4*)(src + tid * 8);
  float4 x1 = *(const float4*)(src + tid * 8 + 4);
  float ss = x0.x * x0.x + x0.y * x0.y + x0.z * x0.z + x0.w * x0.w +
             x1.x * x1.x + x1.y * x1.y + x1.z * x1.z + x1.w * x1.w;
  for (int o = 32; o; o >>= 1) ss += __shfl_down(ss, o);
  __shared__ float wred[4];
  if (lane == 0) wred[wv] = ss;
  __syncthreads();
  float tot = wred[0] + wred[1] + wred[2] + wred[3];
  float r = rsqrtf(tot * (1.0f / Hh) + 1e-5f);
  const float* wp = w + tid * 8;
  u16* op = out + (size_t)t * Hh + tid * 8;
  float xs[8] = {x0.x, x0.y, x0.z, x0.w, x1.x, x1.y, x1.z, x1.w};
#pragma unroll
  for (int j = 0; j < 8; ++j) op[j] = f2b(xs[j] * r * wp[j]);
}

// ---------------- 256x256 8-phase bf16 GEMM, pair-unrolled (frozen K-loop) ----------------
// EPI 4: interleaved gate/up -> silu(g)*u to Cb [4096][8192]. nb = bn offset (grid split).
template <int EPI>
__global__ __launch_bounds__(512, 2) void gemm256(
    const u16* __restrict__ A, const u16* __restrict__ Bt,
    int N, int Kd, int lda, int gm, int gw, int nb,
    u16* __restrict__ Cb,
    const float* __restrict__ hid, const int* __restrict__ idx,
    const float* __restrict__ hs2, const float* __restrict__ scalev,
    float* __restrict__ Cf) {
  __shared__ u16 lds[65536];
  int bid = blockIdx.x;
  int xcd = bid & 7;
  int i2 = bid >> 3;
  int bm = i2 / gw;
  int bn = xcd * gw + i2 % gw + nb;
  int m0 = bm * 256, n0 = bn * 256;
  int tid = threadIdx.x, lane = tid & 63, wv = tid >> 6;
  int wm = wv >> 2, wn = wv & 3;
  int NT = Kd >> 6;

  int P16 = wv * 64 + lane;
  int blk = P16 >> 3, up = P16 & 7;
  int uu = up ^ (blk & 7);
  int r0 = blk * 2 + (uu >> 2), cg0 = uu & 3;
  const u16* srcA = A + (size_t)(m0 + r0) * lda + cg0 * 8;
  const u16* srcB = Bt + (size_t)(n0 + r0) * Kd + cg0 * 8;
  size_t rsA = (size_t)128 * lda, rsB = (size_t)128 * Kd;

  int offA = swz16(wm * 128 + (lane & 15), lane >> 4) * 8;
  int offB = 32768 + swz16(wn * 64 + (lane & 15), lane >> 4) * 8;
  u16* ldsw = &lds[wv * 512];

  f32x4 acc[8][4] = {};
  B8 aR[4], bR[4];

  gll16(srcB,      ldsw + 32768); gll16(srcB + rsB,      ldsw + 36864);
  gll16(srcA,      ldsw +     0); gll16(srcA + rsA,      ldsw +  4096);
  gll16(srcB + 32, ldsw + 40960); gll16(srcB + 32 + rsB, ldsw + 45056);
  gll16(srcA + 32, ldsw +  8192); gll16(srcA + 32 + rsA, ldsw + 12288);
  gll16(srcB + 64, ldsw + 49152); gll16(srcB + 64 + rsB, ldsw + 53248);
  gll16(srcA + 64, ldsw + 16384); gll16(srcA + 64 + rsA, ldsw + 20480);
  gll16(srcB + 96, ldsw + 57344); gll16(srcB + 96 + rsB, ldsw + 61440);
  asm volatile("s_waitcnt vmcnt(6)" ::: "memory");
  asm volatile("s_barrier" ::: "memory");

  const u16* stA = srcA + 64;
  const u16* stB = srcB + 64;

  auto phase = [&](int abase, int bbase, int mh) {
    if (mh == 0) {
#pragma unroll
      for (int nf = 0; nf < 4; ++nf) bR[nf].u = *(const uint4*)&lds[offB + bbase + nf * 512];
    }
#pragma unroll
    for (int i3 = 0; i3 < 4; ++i3)
      aR[i3].u = *(const uint4*)&lds[offA + abase + (i3 + 4 * mh) * 512];
  };
  auto mfma16 = [&](int mh) {
    asm volatile("s_barrier" ::: "memory");
    asm volatile("s_waitcnt lgkmcnt(0)" ::: "memory");
    __builtin_amdgcn_s_setprio(1);
#pragma unroll
    for (int nf = 0; nf < 4; ++nf)
#pragma unroll
      for (int i3 = 0; i3 < 4; ++i3)
        acc[mh * 4 + i3][nf] =
            __builtin_amdgcn_mfma_f32_16x16x32_bf16(aR[i3].v, bR[nf].v, acc[mh * 4 + i3][nf], 0, 0, 0);
    __builtin_amdgcn_s_setprio(0);
  };

  for (int ktp = 0; ktp < NT; ktp += 2) {
    bool sAll = (ktp < NT - 2);
    phase(0, 0, 0);
    { gll16(stA + 32, ldsw + 24576); gll16(stA + 32 + rsA, ldsw + 28672); }
    mfma16(0);
    asm volatile("s_barrier" ::: "memory");
    phase(0, 0, 1);
    if (sAll) { gll16(stB + 64, ldsw + 32768); gll16(stB + 64 + rsB, ldsw + 36864); }
    mfma16(1);
    asm volatile("s_barrier" ::: "memory");
    phase(8192, 8192, 0);
    if (sAll) { gll16(stA + 64, ldsw + 0); gll16(stA + 64 + rsA, ldsw + 4096); }
    mfma16(0);
    asm volatile("s_barrier" ::: "memory");
    phase(8192, 8192, 1);
    if (sAll) { gll16(stB + 96, ldsw + 40960); gll16(stB + 96 + rsB, ldsw + 45056); }
    mfma16(1);
    if (sAll) asm volatile("s_waitcnt vmcnt(6)" ::: "memory");
    else asm volatile("s_waitcnt vmcnt(0)" ::: "memory");
    asm volatile("s_barrier" ::: "memory");
    phase(16384, 16384, 0);
    if (sAll) { gll16(stA + 96, ldsw + 8192); gll16(stA + 96 + rsA, ldsw + 12288); }
    mfma16(0);
    asm volatile("s_barrier" ::: "memory");
    phase(16384, 16384, 1);
    if (sAll) { gll16(stB + 128, ldsw + 49152); gll16(stB + 128 + rsB, ldsw + 53248); }
    mfma16(1);
    asm volatile("s_barrier" ::: "memory");
    phase(24576, 24576, 0);
    if (sAll) { gll16(stA + 128, ldsw + 16384); gll16(stA + 128 + rsA, ldsw + 20480); }
    mfma16(0);
    asm volatile("s_barrier" ::: "memory");
    phase(24576, 24576, 1);
    if (sAll) { gll16(stB + 160, ldsw + 57344); gll16(stB + 160 + rsB, ldsw + 61440); }
    mfma16(1);
    if (sAll) asm volatile("s_waitcnt vmcnt(6)" ::: "memory");
    asm volatile("s_barrier" ::: "memory");
    stA += 128; stB += 128;
  }

  if (EPI == 4) {
    int gcol0 = ((n0 + wn * 64) >> 1) + (lane & 15);
#pragma unroll
    for (int mf = 0; mf < 8; ++mf) {
#pragma unroll
      for (int rr = 0; rr < 4; ++rr) {
        int row = m0 + wm * 128 + mf * 16 + (lane >> 4) * 4 + rr;
#pragma unroll
        for (int nf = 0; nf < 2; ++nf) {
          float g = acc[mf][nf][rr];
          float u = acc[mf][nf + 2][rr];
          Cb[(size_t)row * 8192 + gcol0 + nf * 16] = f2b(g / (1.0f + __expf(-g)) * u);
        }
      }
    }
    return;
  }

#pragma unroll
  for (int mf = 0; mf < 8; ++mf) {
#pragma unroll
    for (int rr = 0; rr < 4; ++rr) {
      int row = m0 + wm * 128 + mf * 16 + (lane >> 4) * 4 + rr;
#pragma unroll
      for (int nf = 0; nf < 4; ++nf) {
        int col = n0 + wn * 64 + nf * 16 + (lane & 15);
        float v = acc[mf][nf][rr];
        if (EPI == 0) {
          Cb[(size_t)row * N + col] = f2b(v);
        } else if (EPI == 1) {
          int b = row >> 10;
          Cf[(size_t)row * Hh + col] = hid[((size_t)b * Ss + idx[row]) * Hh + col] + v;
        } else {
          int b = row >> 10;
          Cf[((size_t)b * Ss + idx[row]) * Hh + col] = hs2[(size_t)row * Hh + col] + v * scalev[b];
        }
      }
    }
  }
}

// ---------------- 128x256 bf16 GEMM, 3-slot/72KB, 2 blocks/CU ----------------
// Slot s: B at s*8192 (2x4096 halves), A at 24576+s*4096. Stage lead 2 phases,
// vmcnt(3)/phase (awaited loads issued 1 phase ago; 2 blocks/CU cover the gap).
// EPI 3: QKV epilogue — Q,K -> Cb; V (cols>=4096) -> vTout key-PERMUTED per 128-block:
//   w=key&127: a=w>>5,s=(w>>4)&1,b=(w>>2)&3 -> pos (a*4+b)*8+s*4+(w&3)  [matches attn pf packing]
template <int EPI>
__global__ __launch_bounds__(512, 4) void gemm128(
    const u16* __restrict__ A, const u16* __restrict__ Bt,
    int N, int Kd, int lda, int gm, int gw,
    u16* __restrict__ Cb,
    const float* __restrict__ hid, const int* __restrict__ idx,
    const float* __restrict__ hs2, const float* __restrict__ scalev,
    float* __restrict__ Cf, u16* __restrict__ vTout) {
  __shared__ u16 lds[36864];
  int bid = blockIdx.x;
  int xcd = bid & 7;
  int i2 = bid >> 3;
  int bm = i2 / gw;
  int bn = xcd * gw + i2 % gw;
  int m0 = bm * 128, n0 = bn * 256;
  int tid = threadIdx.x, lane = tid & 63, wv = tid >> 6;
  int wm = wv >> 2, wn = wv & 3;
  int NT = Kd >> 6;
  int P = NT * 2;

  int P16 = wv * 64 + lane;
  int blk = P16 >> 3, up = P16 & 7;
  int uu = up ^ (blk & 7);
  int r0 = blk * 2 + (uu >> 2), cg0 = uu & 3;
  const u16* srcA = A + (size_t)(m0 + r0) * lda + cg0 * 8;
  const u16* srcB = Bt + (size_t)(n0 + r0) * Kd + cg0 * 8;
  size_t rsB = (size_t)128 * Kd;

  int offB = swz16(wn * 64 + (lane & 15), lane >> 4) * 8;
  int offA = swz16(wm * 64 + (lane & 15), lane >> 4) * 8;
  u16* ldsw = &lds[wv * 512];

  f32x4 acc[4][4] = {};
  B8 aR[4], bR[4];

  auto stage = [&](int q, int bB, int aB) {
    const u16* spB = srcB + q * 32;
    gll16(spB, ldsw + bB);
    gll16(spB + rsB, ldsw + bB + 4096);
    gll16(srcA + q * 32, ldsw + aB);
  };

  stage(0, 0, 24576);
  stage(1, 8192, 28672);
  asm volatile("s_waitcnt vmcnt(3)" ::: "memory");
  asm volatile("s_barrier" ::: "memory");

  int rB = 0, rA = 24576;
  int tB = 16384, tA = 32768;
  for (int p = 0; p < P; ++p) {
#pragma unroll
    for (int f = 0; f < 4; ++f) bR[f].u = *(const uint4*)&lds[rB + offB + f * 512];
#pragma unroll
    for (int f = 0; f < 4; ++f) aR[f].u = *(const uint4*)&lds[rA + offA + f * 512];
    if (p + 2 < P) stage(p + 2, tB, tA);
    asm volatile("s_barrier" ::: "memory");
    asm volatile("s_waitcnt lgkmcnt(0)" ::: "memory");
    __builtin_amdgcn_s_setprio(1);
#pragma unroll
    for (int nf = 0; nf < 4; ++nf)
#pragma unroll
      for (int mf = 0; mf < 4; ++mf)
        acc[mf][nf] = __builtin_amdgcn_mfma_f32_16x16x32_bf16(aR[mf].v, bR[nf].v, acc[mf][nf], 0, 0, 0);
    __builtin_amdgcn_s_setprio(0);
    if (p < P - 2) asm volatile("s_waitcnt vmcnt(3)" ::: "memory");
    else if (p == P - 2) asm volatile("s_waitcnt vmcnt(0)" ::: "memory");
    asm volatile("s_barrier" ::: "memory");
    tB = rB; tA = rA;
    rB = (rB == 16384) ? 0 : rB + 8192;
    rA = (rA == 32768) ? 24576 : rA + 4096;
  }

  if (EPI == 3) {
#pragma unroll
    for (int mf = 0; mf < 4; ++mf) {
      int rowb = m0 + wm * 64 + mf * 16 + (lane >> 4) * 4;
      int bb = rowb >> 10, kk2 = rowb & 1023;
      int w = kk2 & 127;
      int kk2p = (kk2 & ~127) | (((((w >> 5) & 3) << 2) + ((w >> 2) & 3)) << 3) | (((w >> 4) & 1) << 2);
#pragma unroll
      for (int nf = 0; nf < 4; ++nf) {
        int col = n0 + wn * 64 + nf * 16 + (lane & 15);
        if (col >= 4096) {
          int hh = (col - 4096) >> 7, dd = (col - 4096) & 127;
          ushort4 pk;
          pk.x = f2b(acc[mf][nf][0]); pk.y = f2b(acc[mf][nf][1]);
          pk.z = f2b(acc[mf][nf][2]); pk.w = f2b(acc[mf][nf][3]);
          *(ushort4*)&vTout[(((size_t)bb * 16 + hh) * 128 + dd) * 1024 + kk2p] = pk;
        } else {
#pragma unroll
          for (int rr = 0; rr < 4; ++rr)
            Cb[(size_t)(rowb + rr) * N + col] = f2b(acc[mf][nf][rr]);
        }
      }
    }
    return;
  }

#pragma unroll
  for (int mf = 0; mf < 4; ++mf) {
#pragma unroll
    for (int rr = 0; rr < 4; ++rr) {
      int row = m0 + wm * 64 + mf * 16 + (lane >> 4) * 4 + rr;
#pragma unroll
      for (int nf = 0; nf < 4; ++nf) {
        int col = n0 + wn * 64 + nf * 16 + (lane & 15);
        float v = acc[mf][nf][rr];
        if (EPI == 0) {
          Cb[(size_t)row * N + col] = f2b(v);
        } else if (EPI == 1) {
          int b = row >> 10;
          Cf[(size_t)row * Hh + col] = hid[((size_t)b * Ss + idx[row]) * Hh + col] + v;
        } else {
          int b = row >> 10;
          Cf[((size_t)b * Ss + idx[row]) * Hh + col] = hs2[(size_t)row * Hh + col] + v * scalev[b];
        }
      }
    }
  }
}

// ---------------- RoPE on fused QKV buffer (stride 6144; Q,K only) ----------------
__global__ __launch_bounds__(256) void rope_qk(u16* __restrict__ qkv,
                                               const int* __restrict__ posg) {
  int gid = blockIdx.x * 256 + threadIdx.x;
  int i = gid & 63;
  int h = (gid >> 6) & 15;
  int t = gid >> 10;
  float p = (float)posg[t];
  float inv = exp2f(-(float)i * (13.287712379549449f / 64.0f));
  float ang = p * inv;
  float sv, cv;
  __sincosf(ang, &sv, &cv);
  size_t base = (size_t)t * 6144 + h * DHh + i;
  u16* Q = qkv;
  u16* Kq = qkv + 2048;
  float q1 = b2f(Q[base]), q2 = b2f(Q[base + 64]);
  Q[base] = f2b(q1 * cv - q2 * sv);
  Q[base + 64] = f2b(q2 * cv + q1 * sv);
  float k1 = b2f(Kq[base]), k2 = b2f(Kq[base + 64]);
  Kq[base] = f2b(k1 * cv - k2 * sv);
  Kq[base + 64] = f2b(k2 * cv + k1 * sv);
}

// ---------------- flash attention: KVBLK=128, register-P (no LDS bounce), split K/V waits ----------------
// LDS 64KB -> 2 blocks/CU. K staged via gll16 with ^(row&7) unit swizzle; V^T staged from
// key-permuted vT so pf[kslot]={st[2k][0..3],st[2k+1][0..3]} pairs directly with VtA units.
__global__ __launch_bounds__(256) void attn_k(const u16* __restrict__ QKV,
                                              const u16* __restrict__ vT,
                                              u16* __restrict__ O) {
  int qb = blockIdx.x;
  int head = blockIdx.y;
  int b = head >> 4, h = head & 15;
  int tid = threadIdx.x, lane = tid & 63, wv = tid >> 6;
  int l15 = lane & 15, lq = lane >> 4, l7 = lane & 7;
  __shared__ __align__(16) u16 KsA[16384];
  __shared__ __align__(16) u16 VtA[16384];

  int rr0 = tid >> 4;
  int u0 = tid & 15;
  size_t koff0 = (size_t)rr0 * 6144 + ((u0 ^ (rr0 & 7)) * 8);
  size_t voff0 = (size_t)rr0 * 1024 + ((u0 ^ (rr0 & 7)) * 8);
  char* dK = (char*)KsA + wv * 1024;
  char* dV = (char*)VtA + wv * 1024;

  int q0 = qb * 64 + wv * 16;
  int tokQ = b * KS + q0;
  B8 qf[4];
  const u16* qp = QKV + (size_t)(tokQ + l15) * 6144 + h * DHh;
#pragma unroll
  for (int c = 0; c < 4; ++c) qf[c].u = *(const uint4*)(qp + c * 32 + lq * 8);
  float m_run = -1e30f, l_run = 0.0f;
  f32x4 oacc[8] = {};
  int qi = q0 + l15;

  int nt = (qb >> 1) + 1;
  for (int t = 0; t < nt; ++t) {
    int ks = t * 128;
    bool maskTile = (t == nt - 1);
    __syncthreads();  // WAR: prev tile's KsA/VtA reads complete
    const u16* kp = QKV + (size_t)(b * KS + ks) * 6144 + 2048 + h * DHh + koff0;
    const u16* vp = vT + (size_t)head * 131072 + ks + voff0;
#pragma unroll
    for (int i = 0; i < 8; ++i) gll16(kp + (size_t)i * 98304, dK + i * 4096);
#pragma unroll
    for (int i = 0; i < 8; ++i) gll16(vp + i * 16384, dV + i * 4096);
    asm volatile("s_waitcnt vmcnt(8)" ::: "memory");  // K landed (V still in flight)
    __syncthreads();
    // QK^T: st[kt] = S^T (rows=key kt*16.., cols=q)
    f32x4 st[8] = {};
#pragma unroll
    for (int c = 0; c < 4; ++c) {
#pragma unroll
      for (int kt = 0; kt < 8; ++kt) {
        B8 kf;
        kf.u = *(const uint4*)&KsA[(kt * 16 + l15) * 128 + (((c * 4 + lq) ^ l7) * 8)];
        st[kt] = __builtin_amdgcn_mfma_f32_16x16x32_bf16(kf.v, qf[c].v, st[kt], 0, 0, 0);
      }
    }
    float pmax = -INFINITY;
    if (maskTile) {
#pragma unroll
      for (int kt = 0; kt < 8; ++kt)
#pragma unroll
        for (int r = 0; r < 4; ++r) {
          int ki = ks + kt * 16 + lq * 4 + r;
          float v = st[kt][r] * 0.088388347648318447f;
          v = (ki <= qi) ? v : -INFINITY;
          st[kt][r] = v;
          pmax = fmaxf(pmax, v);
        }
    } else {
#pragma unroll
      for (int kt = 0; kt < 8; ++kt)
#pragma unroll
        for (int r = 0; r < 4; ++r) {
          float v = st[kt][r] * 0.088388347648318447f;
          st[kt][r] = v;
          pmax = fmaxf(pmax, v);
        }
    }
    pmax = fmaxf(pmax, __shfl_xor(pmax, 16));
    pmax = fmaxf(pmax, __shfl_xor(pmax, 32));
    float m_new = fmaxf(m_run, pmax);
    float alpha = __expf(m_run - m_new);
    float psum = 0.0f;
#pragma unroll
    for (int kt = 0; kt < 8; ++kt)
#pragma unroll
      for (int r = 0; r < 4; ++r) {
        float pv = __expf(st[kt][r] - m_new);
        st[kt][r] = pv;
        psum += pv;
      }
    psum += __shfl_xor(psum, 16);
    psum += __shfl_xor(psum, 32);
    l_run = l_run * alpha + psum;
    m_run = m_new;
    asm volatile("s_waitcnt vmcnt(0)" ::: "memory");  // own V landed (hidden under QK+softmax)
    __syncthreads();                                  // all waves' V landed
    // pack P fragments locally (keys match permuted VtA units)
    B8 pf[4];
#pragma unroll
    for (int kslot = 0; kslot < 4; ++kslot)
#pragma unroll
      for (int j = 0; j < 4; ++j) {
        pf[kslot].s[j] = f2b(st[2 * kslot][j]);
        pf[kslot].s[4 + j] = f2b(st[2 * kslot + 1][j]);
      }
    float al0 = __shfl(alpha, lq * 4 + 0);
    float al1 = __shfl(alpha, lq * 4 + 1);
    float al2 = __shfl(alpha, lq * 4 + 2);
    float al3 = __shfl(alpha, lq * 4 + 3);
#pragma unroll
    for (int dt = 0; dt < 8; ++dt) {
      oacc[dt][0] *= al0; oacc[dt][1] *= al1;
      oacc[dt][2] *= al2; oacc[dt][3] *= al3;
    }
#pragma unroll
    for (int dt = 0; dt < 8; ++dt) {
      int d = dt * 16 + l15;
#pragma unroll
      for (int kslot = 0; kslot < 4; ++kslot) {
        B8 vf;
        vf.u = *(const uint4*)&VtA[d * 128 + (((kslot * 4 + lq) ^ l7) * 8)];
        oacc[dt] = __builtin_amdgcn_mfma_f32_16x16x32_bf16(pf[kslot].v, vf.v, oacc[dt], 0, 0, 0);
      }
    }
  }
  float linv = 1.0f / l_run;
  float li[4];
#pragma unroll
  for (int r = 0; r < 4; ++r) li[r] = __shfl(linv, lq * 4 + r);
#pragma unroll
  for (int r = 0; r < 4; ++r) {
    int tok = tokQ + lq * 4 + r;
    u16* op = O + (size_t)tok * Hh + h * DHh;
#pragma unroll
    for (int dt = 0; dt < 8; ++dt) op[dt * 16 + l15] = f2b(oacc[dt][r] * li[r]);
  }
}

extern "C" void kernel_launch(void* const* d_in, const int* in_sizes, int n_in,
                              void* d_out, int out_size, void* d_ws, size_t ws_size,
                              hipStream_t stream) {
  (void)in_sizes; (void)n_in; (void)out_size; (void)ws_size;
  const float* hid = (const float*)d_in[0];
  const int* posids = (const int*)d_in[1];
  const void* mask = d_in[2];
  const float* scores = (const float*)d_in[3];
  const float* Wq = (const float*)d_in[5];
  const float* Wk = (const float*)d_in[6];
  const float* Wv = (const float*)d_in[7];
  const float* Wo = (const float*)d_in[8];
  const float* Wg = (const float*)d_in[9];
  const float* Wu = (const float*)d_in[10];
  const float* Wd = (const float*)d_in[11];
  const float* ln1 = (const float*)d_in[12];
  const float* ln2 = (const float*)d_in[13];
  float* out = (float*)d_out;
  char* ws = (char*)d_ws;

  u16* WqkvT = (u16*)(ws + 0);            // [6144][2048] bf16
  u16* WoT   = (u16*)(ws + 25165824);     // [2048][2048]
  u16* WguT  = (u16*)(ws + 33554432);     // [16384][2048] interleaved g/u per 64-row block
  u16* WdT   = (u16*)(ws + 100663296);    // [2048][8192]
  int* idx   = (int*)(ws + 134217728);
  int* posg  = (int*)(ws + 134217728 + 16384);
  float* scalev = (float*)(ws + 134217728 + 32768);
  char* R = ws + 134283264;               // 128MiB pool
  u16* hsn    = (u16*)(R);                // [4096][2048]
  u16* qkv    = (u16*)(R + 16777216);     // [4096][6144] (V third unused)
  u16* attn_o = (u16*)(R + 67108864);     // [4096][2048]
  u16* vT     = (u16*)(R + 88080384);     // [64][128][1024] key-permuted per 128-block
  u16* gu2    = (u16*)(R);                // [4096][8192] silu(g)*u, overlays (dead)
  float* hs2  = (float*)(ws + 268500992); // [4096][2048] f32
  u16* mnorm  = (u16*)(ws + 302055424);   // [4096][2048]

  hipMemcpyAsync(out, hid, (size_t)Bb * Ss * Hh * 4, hipMemcpyDeviceToDevice, stream);

  topk_prep<<<Bb, 256, 0, stream>>>(mask, posids, scores, idx, posg, scalev);

  transpose_w<0><<<dim3(64, 64), dim3(32, 8), 0, stream>>>(Wq, WqkvT, 2048, 2048);
  transpose_w<0><<<dim3(64, 64), dim3(32, 8), 0, stream>>>(Wk, WqkvT + 2048 * 2048, 2048, 2048);
  transpose_w<0><<<dim3(64, 64), dim3(32, 8), 0, stream>>>(Wv, WqkvT + 4096 * 2048, 2048, 2048);
  transpose_w<0><<<dim3(64, 64), dim3(32, 8), 0, stream>>>(Wo, WoT, 2048, 2048);
  transpose_w<1><<<dim3(256, 64), dim3(32, 8), 0, stream>>>(Wg, WguT, 2048, 8192);
  transpose_w<2><<<dim3(256, 64), dim3(32, 8), 0, stream>>>(Wu, WguT, 2048, 8192);
  transpose_w<0><<<dim3(64, 256), dim3(32, 8), 0, stream>>>(Wd, WdT, 8192, 2048);

  rmsnorm_k<1><<<NTOK, 256, 0, stream>>>(hid, idx, ln1, hsn);

  // QKV fused: gemm128 EPI=3 (Q,K -> qkv; V -> vT key-permuted transposed)
  gemm128<3><<<768, 512, 0, stream>>>(hsn, WqkvT, 6144, 2048, 2048, 32, 3, qkv,
                                      nullptr, nullptr, nullptr, nullptr, nullptr, vT);

  rope_qk<<<16384, 256, 0, stream>>>(qkv, posg);

  attn_k<<<dim3(16, 64), 256, 0, stream>>>(qkv, vT, attn_o);

  // Wo: gemm128 (gm=32, gw=1) 256 blocks
  gemm128<1><<<256, 512, 0, stream>>>(attn_o, WoT, 2048, 2048, 2048, 32, 1, nullptr,
                                      hid, idx, nullptr, nullptr, hs2, nullptr);

  rmsnorm_k<0><<<NTOK, 256, 0, stream>>>(hs2, nullptr, ln2, mnorm);

  // gate|up fused + silu epilogue: split into 2x512-block dispatches (instrumentation + same work)
  gemm256<4><<<512, 512, 0, stream>>>(mnorm, WguT, 16384, 2048, 2048, 16, 4, 0, gu2,
                                      nullptr, nullptr, nullptr, nullptr, nullptr);
  gemm256<4><<<512, 512, 0, stream>>>(mnorm, WguT, 16384, 2048, 2048, 16, 4, 32, gu2,
                                      nullptr, nullptr, nullptr, nullptr, nullptr);

  // down: gemm128 (gm=32, gw=1) 256 blocks, A = gu2 (lda 8192, K 8192)
  gemm128<2><<<256, 512, 0, stream>>>(gu2, WdT, 2048, 8192, 8192, 32, 1, nullptr,
                                      nullptr, idx, hs2, scalev, out, nullptr);
}

// Round 12
// 971.658 us; speedup vs baseline: 1.3035x; 1.0650x over previous
//
#include <hip/hip_runtime.h>
#include <hip/hip_bf16.h>
#include <stdint.h>

#define Bb 4
#define Ss 8192
#define Hh 2048
#define NHh 16
#define DHh 128
#define DFFf 8192
#define KS 1024
#define NTOK 4096

typedef unsigned short u16;
typedef __bf16 bf16x8 __attribute__((ext_vector_type(8)));
typedef float f32x4 __attribute__((ext_vector_type(4)));

union B8 { uint4 u; bf16x8 v; u16 s[8]; };

__device__ __forceinline__ float b2f(u16 x) { return __uint_as_float(((unsigned)x) << 16); }
__device__ __forceinline__ u16 f2b(float x) {
  __hip_bfloat16 h = __float2bfloat16(x);
  return *reinterpret_cast<u16*>(&h);
}

__device__ __forceinline__ void gll16(const void* g, void* l) {
  __builtin_amdgcn_global_load_lds((const __attribute__((address_space(1))) void*)g,
                                   (__attribute__((address_space(3))) void*)l, 16, 0, 0);
}

__device__ __forceinline__ int swz16(int r, int cg) {
  int u = ((r & 1) << 2) | cg;
  return ((r >> 1) << 3) | (u ^ ((r >> 1) & 7));
}

// ---------------- top-k index scan ----------------
__global__ void topk_prep(const void* maskp, const int* __restrict__ posids,
                          const float* __restrict__ scores,
                          int* __restrict__ idx, int* __restrict__ posg,
                          float* __restrict__ scalev) {
  int b = blockIdx.x;
  int tid = threadIdx.x, lane = tid & 63, wv = tid >> 6;
  __shared__ int wsum[4];
  __shared__ int base;
  __shared__ int mode;
  __shared__ int detCnt;
  if (tid == 0) { base = 0; detCnt = 0; }
  __syncthreads();
  {
    const unsigned char* mb = (const unsigned char*)maskp;
    int c = 0;
    for (int s = tid; s < 8192; s += 256) c += (mb[s] != 0);
    atomicAdd(&detCnt, c);
  }
  __syncthreads();
  if (tid == 0) mode = (detCnt == KS) ? 1 : 0;
  __syncthreads();
  const unsigned char* mb = (const unsigned char*)maskp;
  const int* mi = (const int*)maskp;
  for (int s0 = 0; s0 < Ss; s0 += 256) {
    int s = s0 + tid;
    int pred = mode ? (mb[(size_t)b * Ss + s] != 0) : (mi[(size_t)b * Ss + s] != 0);
    unsigned long long bal = __ballot(pred);
    int lp = __popcll(bal & ((1ull << lane) - 1ull));
    int wtot = __popcll(bal);
    if (lane == 0) wsum[wv] = wtot;
    __syncthreads();
    int woff = 0;
    for (int w = 0; w < wv; ++w) woff += wsum[w];
    int tot = wsum[0] + wsum[1] + wsum[2] + wsum[3];
    int p = base + woff + lp;
    if (pred && p < KS) {
      idx[b * KS + p] = s;
      posg[b * KS + p] = posids[(size_t)b * Ss + s];
    }
    __syncthreads();
    if (tid == 0) base += tot;
    __syncthreads();
  }
  if (b == 0 && tid < Bb) scalev[tid] = 0.5f * 1.0f + (scores[tid] - 0.5f) * 1.0f;
}

// ---------------- weight transpose fp32 -> bf16 (64x32 tile, vectorized stores) ----------------
// MODE 0: out row = c. MODE 1 (gate): row = (c>>5)*64 + (c&31). MODE 2 (up): +32.
template <int MODE>
__global__ __launch_bounds__(256) void transpose_w(const float* __restrict__ in,
                                                   u16* __restrict__ out, int R, int C) {
  __shared__ float tile[64][33];
  int t = threadIdx.x;
  int c0 = blockIdx.x * 32, r0 = blockIdx.y * 64;
  int tx = t & 31, ty = t >> 5;
#pragma unroll
  for (int j = 0; j < 8; ++j)
    tile[j * 8 + ty][tx] = in[(size_t)(r0 + j * 8 + ty) * C + c0 + tx];
  __syncthreads();
  int c = t >> 3, g = t & 7;
  int cc = c0 + c;
  size_t row = (MODE == 0) ? (size_t)cc
                           : (size_t)((cc >> 5) << 6) + (cc & 31) + (MODE == 2 ? 32 : 0);
  B8 pk;
#pragma unroll
  for (int k = 0; k < 8; ++k) pk.s[k] = f2b(tile[g * 8 + k][c]);
  *(uint4*)&out[row * R + r0 + g * 8] = pk.u;
}

// ---------------- RMSNorm ----------------
template <int GATHER>
__global__ __launch_bounds__(256) void rmsnorm_k(const float* __restrict__ src0,
                                                 const int* __restrict__ idx,
                                                 const float* __restrict__ w,
                                                 u16* __restrict__ out) {
  int t = blockIdx.x;
  const float* src;
  if (GATHER) { int b = t >> 10; src = src0 + ((size_t)b * Ss + idx[t]) * Hh; }
  else src = src0 + (size_t)t * Hh;
  int tid = threadIdx.x, lane = tid & 63, wv = tid >> 6;
  float4 x0 = *(const float4*)(src + tid * 8);
  float4 x1 = *(const float4*)(src + tid * 8 + 4);
  float ss = x0.x * x0.x + x0.y * x0.y + x0.z * x0.z + x0.w * x0.w +
             x1.x * x1.x + x1.y * x1.y + x1.z * x1.z + x1.w * x1.w;
  for (int o = 32; o; o >>= 1) ss += __shfl_down(ss, o);
  __shared__ float wred[4];
  if (lane == 0) wred[wv] = ss;
  __syncthreads();
  float tot = wred[0] + wred[1] + wred[2] + wred[3];
  float r = rsqrtf(tot * (1.0f / Hh) + 1e-5f);
  const float* wp = w + tid * 8;
  u16* op = out + (size_t)t * Hh + tid * 8;
  float xs[8] = {x0.x, x0.y, x0.z, x0.w, x1.x, x1.y, x1.z, x1.w};
#pragma unroll
  for (int j = 0; j < 8; ++j) op[j] = f2b(xs[j] * r * wp[j]);
}

// ---------------- 256x256 8-phase bf16 GEMM, pair-unrolled (frozen K-loop) ----------------
// EPI 4: interleaved gate/up -> silu(g)*u to Cb [4096][8192]. nb = bn offset.
template <int EPI>
__global__ __launch_bounds__(512, 2) void gemm256(
    const u16* __restrict__ A, const u16* __restrict__ Bt,
    int N, int Kd, int lda, int gm, int gw, int nb,
    u16* __restrict__ Cb,
    const float* __restrict__ hid, const int* __restrict__ idx,
    const float* __restrict__ hs2, const float* __restrict__ scalev,
    float* __restrict__ Cf) {
  __shared__ u16 lds[65536];
  int bid = blockIdx.x;
  int xcd = bid & 7;
  int i2 = bid >> 3;
  int bm = i2 / gw;
  int bn = xcd * gw + i2 % gw + nb;
  int m0 = bm * 256, n0 = bn * 256;
  int tid = threadIdx.x, lane = tid & 63, wv = tid >> 6;
  int wm = wv >> 2, wn = wv & 3;
  int NT = Kd >> 6;

  int P16 = wv * 64 + lane;
  int blk = P16 >> 3, up = P16 & 7;
  int uu = up ^ (blk & 7);
  int r0 = blk * 2 + (uu >> 2), cg0 = uu & 3;
  const u16* srcA = A + (size_t)(m0 + r0) * lda + cg0 * 8;
  const u16* srcB = Bt + (size_t)(n0 + r0) * Kd + cg0 * 8;
  size_t rsA = (size_t)128 * lda, rsB = (size_t)128 * Kd;

  int offA = swz16(wm * 128 + (lane & 15), lane >> 4) * 8;
  int offB = 32768 + swz16(wn * 64 + (lane & 15), lane >> 4) * 8;
  u16* ldsw = &lds[wv * 512];

  f32x4 acc[8][4] = {};
  B8 aR[4], bR[4];

  gll16(srcB,      ldsw + 32768); gll16(srcB + rsB,      ldsw + 36864);
  gll16(srcA,      ldsw +     0); gll16(srcA + rsA,      ldsw +  4096);
  gll16(srcB + 32, ldsw + 40960); gll16(srcB + 32 + rsB, ldsw + 45056);
  gll16(srcA + 32, ldsw +  8192); gll16(srcA + 32 + rsA, ldsw + 12288);
  gll16(srcB + 64, ldsw + 49152); gll16(srcB + 64 + rsB, ldsw + 53248);
  gll16(srcA + 64, ldsw + 16384); gll16(srcA + 64 + rsA, ldsw + 20480);
  gll16(srcB + 96, ldsw + 57344); gll16(srcB + 96 + rsB, ldsw + 61440);
  asm volatile("s_waitcnt vmcnt(6)" ::: "memory");
  asm volatile("s_barrier" ::: "memory");

  const u16* stA = srcA + 64;
  const u16* stB = srcB + 64;

  auto phase = [&](int abase, int bbase, int mh) {
    if (mh == 0) {
#pragma unroll
      for (int nf = 0; nf < 4; ++nf) bR[nf].u = *(const uint4*)&lds[offB + bbase + nf * 512];
    }
#pragma unroll
    for (int i3 = 0; i3 < 4; ++i3)
      aR[i3].u = *(const uint4*)&lds[offA + abase + (i3 + 4 * mh) * 512];
  };
  auto mfma16 = [&](int mh) {
    asm volatile("s_barrier" ::: "memory");
    asm volatile("s_waitcnt lgkmcnt(0)" ::: "memory");
    __builtin_amdgcn_s_setprio(1);
#pragma unroll
    for (int nf = 0; nf < 4; ++nf)
#pragma unroll
      for (int i3 = 0; i3 < 4; ++i3)
        acc[mh * 4 + i3][nf] =
            __builtin_amdgcn_mfma_f32_16x16x32_bf16(aR[i3].v, bR[nf].v, acc[mh * 4 + i3][nf], 0, 0, 0);
    __builtin_amdgcn_s_setprio(0);
  };

  for (int ktp = 0; ktp < NT; ktp += 2) {
    bool sAll = (ktp < NT - 2);
    phase(0, 0, 0);
    { gll16(stA + 32, ldsw + 24576); gll16(stA + 32 + rsA, ldsw + 28672); }
    mfma16(0);
    asm volatile("s_barrier" ::: "memory");
    phase(0, 0, 1);
    if (sAll) { gll16(stB + 64, ldsw + 32768); gll16(stB + 64 + rsB, ldsw + 36864); }
    mfma16(1);
    asm volatile("s_barrier" ::: "memory");
    phase(8192, 8192, 0);
    if (sAll) { gll16(stA + 64, ldsw + 0); gll16(stA + 64 + rsA, ldsw + 4096); }
    mfma16(0);
    asm volatile("s_barrier" ::: "memory");
    phase(8192, 8192, 1);
    if (sAll) { gll16(stB + 96, ldsw + 40960); gll16(stB + 96 + rsB, ldsw + 45056); }
    mfma16(1);
    if (sAll) asm volatile("s_waitcnt vmcnt(6)" ::: "memory");
    else asm volatile("s_waitcnt vmcnt(0)" ::: "memory");
    asm volatile("s_barrier" ::: "memory");
    phase(16384, 16384, 0);
    if (sAll) { gll16(stA + 96, ldsw + 8192); gll16(stA + 96 + rsA, ldsw + 12288); }
    mfma16(0);
    asm volatile("s_barrier" ::: "memory");
    phase(16384, 16384, 1);
    if (sAll) { gll16(stB + 128, ldsw + 49152); gll16(stB + 128 + rsB, ldsw + 53248); }
    mfma16(1);
    asm volatile("s_barrier" ::: "memory");
    phase(24576, 24576, 0);
    if (sAll) { gll16(stA + 128, ldsw + 16384); gll16(stA + 128 + rsA, ldsw + 20480); }
    mfma16(0);
    asm volatile("s_barrier" ::: "memory");
    phase(24576, 24576, 1);
    if (sAll) { gll16(stB + 160, ldsw + 57344); gll16(stB + 160 + rsB, ldsw + 61440); }
    mfma16(1);
    if (sAll) asm volatile("s_waitcnt vmcnt(6)" ::: "memory");
    asm volatile("s_barrier" ::: "memory");
    stA += 128; stB += 128;
  }

  if (EPI == 4) {
    int gcol0 = ((n0 + wn * 64) >> 1) + (lane & 15);
#pragma unroll
    for (int mf = 0; mf < 8; ++mf) {
#pragma unroll
      for (int rr = 0; rr < 4; ++rr) {
        int row = m0 + wm * 128 + mf * 16 + (lane >> 4) * 4 + rr;
#pragma unroll
        for (int nf = 0; nf < 2; ++nf) {
          float g = acc[mf][nf][rr];
          float u = acc[mf][nf + 2][rr];
          Cb[(size_t)row * 8192 + gcol0 + nf * 16] = f2b(g / (1.0f + __expf(-g)) * u);
        }
      }
    }
    return;
  }

#pragma unroll
  for (int mf = 0; mf < 8; ++mf) {
#pragma unroll
    for (int rr = 0; rr < 4; ++rr) {
      int row = m0 + wm * 128 + mf * 16 + (lane >> 4) * 4 + rr;
#pragma unroll
      for (int nf = 0; nf < 4; ++nf) {
        int col = n0 + wn * 64 + nf * 16 + (lane & 15);
        float v = acc[mf][nf][rr];
        if (EPI == 0) {
          Cb[(size_t)row * N + col] = f2b(v);
        } else if (EPI == 1) {
          int b = row >> 10;
          Cf[(size_t)row * Hh + col] = hid[((size_t)b * Ss + idx[row]) * Hh + col] + v;
        } else {
          int b = row >> 10;
          Cf[((size_t)b * Ss + idx[row]) * Hh + col] = hs2[(size_t)row * Hh + col] + v * scalev[b];
        }
      }
    }
  }
}

// ---------------- 128x256 bf16 GEMM, 3-slot/36KB, pipelined ----------------
// r2d=1: 2D XCD raster (xr,xc)=(xcd>>1,xcd&1); XCD owns 8bm x 4bn (for M=4096,N=2048 grids).
// EPI 3: QKV epilogue — Q,K -> Cb; V (cols>=4096) -> vTout key-PERMUTED per 128-block.
template <int EPI>
__global__ __launch_bounds__(512, 4) void gemm128(
    const u16* __restrict__ A, const u16* __restrict__ Bt,
    int N, int Kd, int lda, int gm, int gw, int r2d,
    u16* __restrict__ Cb,
    const float* __restrict__ hid, const int* __restrict__ idx,
    const float* __restrict__ hs2, const float* __restrict__ scalev,
    float* __restrict__ Cf, u16* __restrict__ vTout) {
  __shared__ u16 lds[36864];
  int bid = blockIdx.x;
  int xcd = bid & 7;
  int i2 = bid >> 3;
  int bm, bn;
  if (r2d) {
    int xr = xcd >> 1, xc = xcd & 1;
    bm = xr * 8 + (i2 & 7);
    bn = xc * 4 + (i2 >> 3);
  } else {
    bm = i2 / gw;
    bn = xcd * gw + i2 % gw;
  }
  int m0 = bm * 128, n0 = bn * 256;
  int tid = threadIdx.x, lane = tid & 63, wv = tid >> 6;
  int wm = wv >> 2, wn = wv & 3;
  int NT = Kd >> 6;
  int P = NT * 2;

  int P16 = wv * 64 + lane;
  int blk = P16 >> 3, up = P16 & 7;
  int uu = up ^ (blk & 7);
  int r0 = blk * 2 + (uu >> 2), cg0 = uu & 3;
  const u16* srcA = A + (size_t)(m0 + r0) * lda + cg0 * 8;
  const u16* srcB = Bt + (size_t)(n0 + r0) * Kd + cg0 * 8;
  size_t rsB = (size_t)128 * Kd;

  int offB = swz16(wn * 64 + (lane & 15), lane >> 4) * 8;
  int offA = swz16(wm * 64 + (lane & 15), lane >> 4) * 8;
  u16* ldsw = &lds[wv * 512];

  f32x4 acc[4][4] = {};
  B8 aR[4], bR[4];

  auto stage = [&](int q, int bB, int aB) {
    const u16* spB = srcB + q * 32;
    gll16(spB, ldsw + bB);
    gll16(spB + rsB, ldsw + bB + 4096);
    gll16(srcA + q * 32, ldsw + aB);
  };

  stage(0, 0, 24576);
  stage(1, 8192, 28672);
  asm volatile("s_waitcnt vmcnt(3)" ::: "memory");
  asm volatile("s_barrier" ::: "memory");

  int rB = 0, rA = 24576;
  int tB = 16384, tA = 32768;
  for (int p = 0; p < P; ++p) {
#pragma unroll
    for (int f = 0; f < 4; ++f) bR[f].u = *(const uint4*)&lds[rB + offB + f * 512];
#pragma unroll
    for (int f = 0; f < 4; ++f) aR[f].u = *(const uint4*)&lds[rA + offA + f * 512];
    if (p + 2 < P) stage(p + 2, tB, tA);
    asm volatile("s_barrier" ::: "memory");
    asm volatile("s_waitcnt lgkmcnt(0)" ::: "memory");
    __builtin_amdgcn_s_setprio(1);
#pragma unroll
    for (int nf = 0; nf < 4; ++nf)
#pragma unroll
      for (int mf = 0; mf < 4; ++mf)
        acc[mf][nf] = __builtin_amdgcn_mfma_f32_16x16x32_bf16(aR[mf].v, bR[nf].v, acc[mf][nf], 0, 0, 0);
    __builtin_amdgcn_s_setprio(0);
    if (p < P - 2) asm volatile("s_waitcnt vmcnt(3)" ::: "memory");
    else if (p == P - 2) asm volatile("s_waitcnt vmcnt(0)" ::: "memory");
    asm volatile("s_barrier" ::: "memory");
    tB = rB; tA = rA;
    rB = (rB == 16384) ? 0 : rB + 8192;
    rA = (rA == 32768) ? 24576 : rA + 4096;
  }

  if (EPI == 3) {
#pragma unroll
    for (int mf = 0; mf < 4; ++mf) {
      int rowb = m0 + wm * 64 + mf * 16 + (lane >> 4) * 4;
      int bb = rowb >> 10, kk2 = rowb & 1023;
      int w = kk2 & 127;
      int kk2p = (kk2 & ~127) | (((((w >> 5) & 3) << 2) + ((w >> 2) & 3)) << 3) | (((w >> 4) & 1) << 2);
#pragma unroll
      for (int nf = 0; nf < 4; ++nf) {
        int col = n0 + wn * 64 + nf * 16 + (lane & 15);
        if (col >= 4096) {
          int hh = (col - 4096) >> 7, dd = (col - 4096) & 127;
          ushort4 pk;
          pk.x = f2b(acc[mf][nf][0]); pk.y = f2b(acc[mf][nf][1]);
          pk.z = f2b(acc[mf][nf][2]); pk.w = f2b(acc[mf][nf][3]);
          *(ushort4*)&vTout[(((size_t)bb * 16 + hh) * 128 + dd) * 1024 + kk2p] = pk;
        } else {
#pragma unroll
          for (int rr = 0; rr < 4; ++rr)
            Cb[(size_t)(rowb + rr) * N + col] = f2b(acc[mf][nf][rr]);
        }
      }
    }
    return;
  }

#pragma unroll
  for (int mf = 0; mf < 4; ++mf) {
#pragma unroll
    for (int rr = 0; rr < 4; ++rr) {
      int row = m0 + wm * 64 + mf * 16 + (lane >> 4) * 4 + rr;
#pragma unroll
      for (int nf = 0; nf < 4; ++nf) {
        int col = n0 + wn * 64 + nf * 16 + (lane & 15);
        float v = acc[mf][nf][rr];
        if (EPI == 0) {
          Cb[(size_t)row * N + col] = f2b(v);
        } else if (EPI == 1) {
          int b = row >> 10;
          Cf[(size_t)row * Hh + col] = hid[((size_t)b * Ss + idx[row]) * Hh + col] + v;
        } else {
          int b = row >> 10;
          Cf[((size_t)b * Ss + idx[row]) * Hh + col] = hs2[(size_t)row * Hh + col] + v * scalev[b];
        }
      }
    }
  }
}

// ---------------- RoPE, 4 pairs/thread, vectorized (Q,K only) ----------------
__global__ __launch_bounds__(256) void rope_qk(u16* __restrict__ qkv,
                                               const int* __restrict__ posg) {
  int gid = blockIdx.x * 256 + threadIdx.x;  // 1M threads
  int i4 = (gid & 15) << 2;
  int h = (gid >> 4) & 15;
  int t = gid >> 8;
  float p = (float)posg[t];
  size_t base = (size_t)t * 6144 + h * DHh + i4;
  u16* Q = qkv;
  u16* Kq = qkv + 2048;
  ushort4 q1 = *(ushort4*)&Q[base], q2 = *(ushort4*)&Q[base + 64];
  ushort4 k1 = *(ushort4*)&Kq[base], k2 = *(ushort4*)&Kq[base + 64];
  u16* q1p = (u16*)&q1; u16* q2p = (u16*)&q2;
  u16* k1p = (u16*)&k1; u16* k2p = (u16*)&k2;
#pragma unroll
  for (int j = 0; j < 4; ++j) {
    int i = i4 + j;
    float inv = exp2f(-(float)i * (13.287712379549449f / 64.0f));
    float sv, cv;
    __sincosf(p * inv, &sv, &cv);
    float a1 = b2f(q1p[j]), a2 = b2f(q2p[j]);
    q1p[j] = f2b(a1 * cv - a2 * sv);
    q2p[j] = f2b(a2 * cv + a1 * sv);
    float c1 = b2f(k1p[j]), c2 = b2f(k2p[j]);
    k1p[j] = f2b(c1 * cv - c2 * sv);
    k2p[j] = f2b(c2 * cv + c1 * sv);
  }
  *(ushort4*)&Q[base] = q1; *(ushort4*)&Q[base + 64] = q2;
  *(ushort4*)&Kq[base] = k1; *(ushort4*)&Kq[base + 64] = k2;
}

// ---------------- flash attention: KVBLK=128, register-P, split K/V waits ----------------
__global__ __launch_bounds__(256) void attn_k(const u16* __restrict__ QKV,
                                              const u16* __restrict__ vT,
                                              u16* __restrict__ O) {
  int qb = blockIdx.x;
  int head = blockIdx.y;
  int b = head >> 4, h = head & 15;
  int tid = threadIdx.x, lane = tid & 63, wv = tid >> 6;
  int l15 = lane & 15, lq = lane >> 4, l7 = lane & 7;
  __shared__ __align__(16) u16 KsA[16384];
  __shared__ __align__(16) u16 VtA[16384];

  int rr0 = tid >> 4;
  int u0 = tid & 15;
  size_t koff0 = (size_t)rr0 * 6144 + ((u0 ^ (rr0 & 7)) * 8);
  size_t voff0 = (size_t)rr0 * 1024 + ((u0 ^ (rr0 & 7)) * 8);
  char* dK = (char*)KsA + wv * 1024;
  char* dV = (char*)VtA + wv * 1024;

  int q0 = qb * 64 + wv * 16;
  int tokQ = b * KS + q0;
  B8 qf[4];
  const u16* qp = QKV + (size_t)(tokQ + l15) * 6144 + h * DHh;
#pragma unroll
  for (int c = 0; c < 4; ++c) qf[c].u = *(const uint4*)(qp + c * 32 + lq * 8);
  float m_run = -1e30f, l_run = 0.0f;
  f32x4 oacc[8] = {};
  int qi = q0 + l15;

  int nt = (qb >> 1) + 1;
  for (int t = 0; t < nt; ++t) {
    int ks = t * 128;
    bool maskTile = (t == nt - 1);
    __syncthreads();
    const u16* kp = QKV + (size_t)(b * KS + ks) * 6144 + 2048 + h * DHh + koff0;
    const u16* vp = vT + (size_t)head * 131072 + ks + voff0;
#pragma unroll
    for (int i = 0; i < 8; ++i) gll16(kp + (size_t)i * 98304, dK + i * 4096);
#pragma unroll
    for (int i = 0; i < 8; ++i) gll16(vp + i * 16384, dV + i * 4096);
    asm volatile("s_waitcnt vmcnt(8)" ::: "memory");
    __syncthreads();
    f32x4 st[8] = {};
#pragma unroll
    for (int c = 0; c < 4; ++c) {
#pragma unroll
      for (int kt = 0; kt < 8; ++kt) {
        B8 kf;
        kf.u = *(const uint4*)&KsA[(kt * 16 + l15) * 128 + (((c * 4 + lq) ^ l7) * 8)];
        st[kt] = __builtin_amdgcn_mfma_f32_16x16x32_bf16(kf.v, qf[c].v, st[kt], 0, 0, 0);
      }
    }
    float pmax = -INFINITY;
    if (maskTile) {
#pragma unroll
      for (int kt = 0; kt < 8; ++kt)
#pragma unroll
        for (int r = 0; r < 4; ++r) {
          int ki = ks + kt * 16 + lq * 4 + r;
          float v = st[kt][r] * 0.088388347648318447f;
          v = (ki <= qi) ? v : -INFINITY;
          st[kt][r] = v;
          pmax = fmaxf(pmax, v);
        }
    } else {
#pragma unroll
      for (int kt = 0; kt < 8; ++kt)
#pragma unroll
        for (int r = 0; r < 4; ++r) {
          float v = st[kt][r] * 0.088388347648318447f;
          st[kt][r] = v;
          pmax = fmaxf(pmax, v);
        }
    }
    pmax = fmaxf(pmax, __shfl_xor(pmax, 16));
    pmax = fmaxf(pmax, __shfl_xor(pmax, 32));
    float m_new = fmaxf(m_run, pmax);
    float alpha = __expf(m_run - m_new);
    float psum = 0.0f;
#pragma unroll
    for (int kt = 0; kt < 8; ++kt)
#pragma unroll
      for (int r = 0; r < 4; ++r) {
        float pv = __expf(st[kt][r] - m_new);
        st[kt][r] = pv;
        psum += pv;
      }
    psum += __shfl_xor(psum, 16);
    psum += __shfl_xor(psum, 32);
    l_run = l_run * alpha + psum;
    m_run = m_new;
    asm volatile("s_waitcnt vmcnt(0)" ::: "memory");
    __syncthreads();
    B8 pf[4];
#pragma unroll
    for (int kslot = 0; kslot < 4; ++kslot)
#pragma unroll
      for (int j = 0; j < 4; ++j) {
        pf[kslot].s[j] = f2b(st[2 * kslot][j]);
        pf[kslot].s[4 + j] = f2b(st[2 * kslot + 1][j]);
      }
    float al0 = __shfl(alpha, lq * 4 + 0);
    float al1 = __shfl(alpha, lq * 4 + 1);
    float al2 = __shfl(alpha, lq * 4 + 2);
    float al3 = __shfl(alpha, lq * 4 + 3);
#pragma unroll
    for (int dt = 0; dt < 8; ++dt) {
      oacc[dt][0] *= al0; oacc[dt][1] *= al1;
      oacc[dt][2] *= al2; oacc[dt][3] *= al3;
    }
#pragma unroll
    for (int dt = 0; dt < 8; ++dt) {
      int d = dt * 16 + l15;
#pragma unroll
      for (int kslot = 0; kslot < 4; ++kslot) {
        B8 vf;
        vf.u = *(const uint4*)&VtA[d * 128 + (((kslot * 4 + lq) ^ l7) * 8)];
        oacc[dt] = __builtin_amdgcn_mfma_f32_16x16x32_bf16(pf[kslot].v, vf.v, oacc[dt], 0, 0, 0);
      }
    }
  }
  float linv = 1.0f / l_run;
  float li[4];
#pragma unroll
  for (int r = 0; r < 4; ++r) li[r] = __shfl(linv, lq * 4 + r);
#pragma unroll
  for (int r = 0; r < 4; ++r) {
    int tok = tokQ + lq * 4 + r;
    u16* op = O + (size_t)tok * Hh + h * DHh;
#pragma unroll
    for (int dt = 0; dt < 8; ++dt) op[dt * 16 + l15] = f2b(oacc[dt][r] * li[r]);
  }
}

extern "C" void kernel_launch(void* const* d_in, const int* in_sizes, int n_in,
                              void* d_out, int out_size, void* d_ws, size_t ws_size,
                              hipStream_t stream) {
  (void)in_sizes; (void)n_in; (void)out_size; (void)ws_size;
  const float* hid = (const float*)d_in[0];
  const int* posids = (const int*)d_in[1];
  const void* mask = d_in[2];
  const float* scores = (const float*)d_in[3];
  const float* Wq = (const float*)d_in[5];
  const float* Wk = (const float*)d_in[6];
  const float* Wv = (const float*)d_in[7];
  const float* Wo = (const float*)d_in[8];
  const float* Wg = (const float*)d_in[9];
  const float* Wu = (const float*)d_in[10];
  const float* Wd = (const float*)d_in[11];
  const float* ln1 = (const float*)d_in[12];
  const float* ln2 = (const float*)d_in[13];
  float* out = (float*)d_out;
  char* ws = (char*)d_ws;

  u16* WqkvT = (u16*)(ws + 0);            // [6144][2048] bf16
  u16* WoT   = (u16*)(ws + 25165824);     // [2048][2048]
  u16* WguT  = (u16*)(ws + 33554432);     // [16384][2048] interleaved g/u per 64-row block
  u16* WdT   = (u16*)(ws + 100663296);    // [2048][8192]
  int* idx   = (int*)(ws + 134217728);
  int* posg  = (int*)(ws + 134217728 + 16384);
  float* scalev = (float*)(ws + 134217728 + 32768);
  char* R = ws + 134283264;               // 128MiB pool
  u16* hsn    = (u16*)(R);                // [4096][2048]
  u16* qkv    = (u16*)(R + 16777216);     // [4096][6144]
  u16* attn_o = (u16*)(R + 67108864);     // [4096][2048]
  u16* vT     = (u16*)(R + 88080384);     // [64][128][1024] key-permuted
  u16* gu2    = (u16*)(R);                // [4096][8192] silu(g)*u (overlays dead bufs)
  float* hs2  = (float*)(ws + 268500992); // [4096][2048] f32
  u16* mnorm  = (u16*)(ws + 302055424);   // [4096][2048]

  hipMemcpyAsync(out, hid, (size_t)Bb * Ss * Hh * 4, hipMemcpyDeviceToDevice, stream);

  topk_prep<<<Bb, 256, 0, stream>>>(mask, posids, scores, idx, posg, scalev);

  transpose_w<0><<<dim3(64, 32), 256, 0, stream>>>(Wq, WqkvT, 2048, 2048);
  transpose_w<0><<<dim3(64, 32), 256, 0, stream>>>(Wk, WqkvT + 2048 * 2048, 2048, 2048);
  transpose_w<0><<<dim3(64, 32), 256, 0, stream>>>(Wv, WqkvT + 4096 * 2048, 2048, 2048);
  transpose_w<0><<<dim3(64, 32), 256, 0, stream>>>(Wo, WoT, 2048, 2048);
  transpose_w<1><<<dim3(256, 32), 256, 0, stream>>>(Wg, WguT, 2048, 8192);
  transpose_w<2><<<dim3(256, 32), 256, 0, stream>>>(Wu, WguT, 2048, 8192);
  transpose_w<0><<<dim3(64, 128), 256, 0, stream>>>(Wd, WdT, 8192, 2048);

  rmsnorm_k<1><<<NTOK, 256, 0, stream>>>(hid, idx, ln1, hsn);

  // QKV fused: gemm128 EPI=3 (Q,K -> qkv; V -> vT key-permuted transposed)
  gemm128<3><<<768, 512, 0, stream>>>(hsn, WqkvT, 6144, 2048, 2048, 32, 3, 0, qkv,
                                      nullptr, nullptr, nullptr, nullptr, nullptr, vT);

  rope_qk<<<4096, 256, 0, stream>>>(qkv, posg);

  attn_k<<<dim3(16, 64), 256, 0, stream>>>(qkv, vT, attn_o);

  // Wo: gemm128 2D raster
  gemm128<1><<<256, 512, 0, stream>>>(attn_o, WoT, 2048, 2048, 2048, 32, 1, 1, nullptr,
                                      hid, idx, nullptr, nullptr, hs2, nullptr);

  rmsnorm_k<0><<<NTOK, 256, 0, stream>>>(hs2, nullptr, ln2, mnorm);

  // gate|up fused + silu epilogue: single 1024-block dispatch
  gemm256<4><<<1024, 512, 0, stream>>>(mnorm, WguT, 16384, 2048, 2048, 16, 8, 0, gu2,
                                       nullptr, nullptr, nullptr, nullptr, nullptr);

  // down: gemm128 2D raster, A = gu2 (lda 8192, K 8192)
  gemm128<2><<<256, 512, 0, stream>>>(gu2, WdT, 2048, 8192, 8192, 32, 1, 1, nullptr,
                                      nullptr, idx, hs2, scalev, out, nullptr);
}